// Round 2
// baseline (799.584 us; speedup 1.0000x reference)
//
#include <hip/hip_runtime.h>
#include <math.h>

#define BB 4
#define NX 4096
#define NYP 8192
#define GG 4096
#define WIDTH 32
#define SS 16
#define PI_F 3.14159265358979323846f

__device__ __forceinline__ float gelu_exact(float v) {
    return 0.5f * v * (1.0f + erff(v * 0.70710678118654752f));
}

// ---------------- embed (2 matvec families) + fc0 -> h0 (B,32,64,64) ----------------
// block handles 2 consecutive g rows; grid 2048 blocks -> 8192 waves = 100% occupancy cap.
__global__ __launch_bounds__(256) void k_embed(
    const float* __restrict__ x, const float* __restrict__ loc,
    const float* __restrict__ We1, const float* __restrict__ be1,
    const float* __restrict__ We2, const float* __restrict__ be2,
    const float* __restrict__ Wfc0, const float* __restrict__ bfc0,
    float* __restrict__ h0)
{
    int gbase = blockIdx.x * 2;
    int t = threadIdx.x;
    float acc[24];
    #pragma unroll
    for (int k = 0; k < 24; ++k) acc[k] = 0.f;

    for (int n4 = t; n4 < NX / 4; n4 += 256) {
        float4 xb[4];
        #pragma unroll
        for (int b = 0; b < 4; ++b)
            xb[b] = ((const float4*)(x + (size_t)b * NX))[n4];
        #pragma unroll
        for (int r = 0; r < 2; ++r) {
            float4 w = ((const float4*)(We1 + (size_t)(gbase + r) * NX))[n4];
            #pragma unroll
            for (int b = 0; b < 4; ++b)
                acc[r * 4 + b] += w.x * xb[b].x + w.y * xb[b].y + w.z * xb[b].z + w.w * xb[b].w;
        }
    }
    for (int n4 = t; n4 < NYP / 4; n4 += 256) {
        float4 p0[4], p1[4];
        #pragma unroll
        for (int b = 0; b < 4; ++b) {
            const float4* lb = (const float4*)(loc + (size_t)b * NYP * 2);
            p0[b] = lb[n4 * 2];
            p1[b] = lb[n4 * 2 + 1];
        }
        #pragma unroll
        for (int r = 0; r < 2; ++r) {
            float4 w = ((const float4*)(We2 + (size_t)(gbase + r) * NYP))[n4];
            #pragma unroll
            for (int b = 0; b < 4; ++b) {
                acc[8 + r * 4 + b]  += w.x * p0[b].x + w.y * p0[b].z + w.z * p1[b].x + w.w * p1[b].z;
                acc[16 + r * 4 + b] += w.x * p0[b].y + w.y * p0[b].w + w.z * p1[b].y + w.w * p1[b].w;
            }
        }
    }
    // wave reduce then cross-wave
    #pragma unroll
    for (int k = 0; k < 24; ++k)
        for (int off = 32; off > 0; off >>= 1) acc[k] += __shfl_down(acc[k], off);
    __shared__ float red[4][24];
    __shared__ float tot[24];
    int wave = t >> 6, lane = t & 63;
    if (lane == 0)
        for (int k = 0; k < 24; ++k) red[wave][k] = acc[k];
    __syncthreads();
    if (t < 24) tot[t] = red[0][t] + red[1][t] + red[2][t] + red[3][t];
    __syncthreads();
    if (t < 128) {
        int b = t >> 5, w = t & 31;
        float w0 = Wfc0[w * 3 + 0], w1c = Wfc0[w * 3 + 1], w2c = Wfc0[w * 3 + 2], bb0 = bfc0[w];
        #pragma unroll
        for (int r = 0; r < 2; ++r) {
            int g = gbase + r;
            float xe = tot[r * 4 + b] + be1[g];
            float l0 = tot[8 + r * 4 + b] + be2[g];
            float l1 = tot[16 + r * 4 + b] + be2[g];
            h0[((size_t)(b * WIDTH + w)) * GG + g] = xe * w0 + l0 * w1c + l1 * w2c + bb0;
        }
    }
}

// ---------------- truncated forward DFT: h(b,c,64,64) -> xf(b,c,16,8) complex ----------------
__global__ __launch_bounds__(256) void k_xf(const float* __restrict__ h, float* __restrict__ xf)
{
    int bc = blockIdx.x;
    int t = threadIdx.x;
    __shared__ float sh[64 * 66];          // padded rows: bank-conflict-free stage-1
    __shared__ float twc[8 * 64], tws[8 * 64];
    __shared__ float s1[64 * 8 * 2];
    const float* hp = h + (size_t)bc * 4096;
    for (int i = t; i < 4096; i += 256) sh[(i >> 6) * 66 + (i & 63)] = hp[i];
    for (int i = t; i < 512; i += 256) {
        int ky = i >> 6, y = i & 63;
        float s, c;
        sincosf(-2.f * PI_F * (float)(ky * y) / 64.f, &s, &c);
        twc[i] = c; tws[i] = s;
    }
    __syncthreads();
    for (int task = t; task < 512; task += 256) {
        int xx = task >> 3, ky = task & 7;
        float sr = 0.f, si = 0.f;
        const float* row = sh + xx * 66;
        const float* tc = twc + ky * 64;
        const float* ts = tws + ky * 64;
        for (int y = 0; y < 64; ++y) { sr += row[y] * tc[y]; si += row[y] * ts[y]; }
        s1[(xx * 8 + ky) * 2 + 0] = sr;
        s1[(xx * 8 + ky) * 2 + 1] = si;
    }
    __syncthreads();
    if (t < 128) {
        int kxi = t >> 3, ky = t & 7;
        int kx = (kxi < 8) ? kxi : (kxi - 16);   // negative freq alias of rows 56..63
        float ar = 0.f, ai = 0.f;
        for (int xx = 0; xx < 64; ++xx) {
            float s, c;
            sincosf(-2.f * PI_F * (float)(kx * xx) / 64.f, &s, &c);
            float vr = s1[(xx * 8 + ky) * 2], vi = s1[(xx * 8 + ky) * 2 + 1];
            ar += vr * c - vi * s;
            ai += vr * s + vi * c;
        }
        xf[((size_t)bc * 128 + t) * 2 + 0] = ar;
        xf[((size_t)bc * 128 + t) * 2 + 1] = ai;
    }
}

// ---------------- mode mix + truncated inverse DFT + pointwise + gelu ----------------
__global__ __launch_bounds__(256) void k_mix_inv(
    const float* __restrict__ h, const float* __restrict__ xf,
    const float* __restrict__ w1, const float* __restrict__ w2,
    const float* __restrict__ wpt, const float* __restrict__ wptb,
    float* __restrict__ hout, int do_gelu)
{
    int blk = blockIdx.x;
    int b = blk >> 5, o = blk & 31;
    int t = threadIdx.x;
    __shared__ float sxf[32 * 128 * 2];   // 32 KB
    __shared__ float sof[128 * 2];
    __shared__ float stt[64 * 8 * 2];
    __shared__ float cy[8 * 64], sy[8 * 64];
    const float* xfb = xf + (size_t)b * 32 * 128 * 2;
    for (int i = t; i < 32 * 128 * 2; i += 256) sxf[i] = xfb[i];
    for (int i = t; i < 512; i += 256) {
        int ky = i >> 6, y = i & 63;
        float s, c;
        sincosf(2.f * PI_F * (float)(ky * y) / 64.f, &s, &c);
        cy[i] = c; sy[i] = s;
    }
    __syncthreads();
    if (t < 128) {                          // of[o] = sum_i xf[i] * w[i,o]
        int kxi = t >> 3, ky = t & 7;
        const float* w = (kxi < 8) ? w1 : w2;
        int kxw = kxi & 7;
        float ar = 0.f, ai = 0.f;
        for (int i = 0; i < 32; ++i) {
            size_t wi0 = (((size_t)(i * 32 + o) * 8 + kxw) * 8 + ky) * 2;
            float wr = w[wi0], wimag = w[wi0 + 1];
            float xr = sxf[(i * 128 + t) * 2], xi = sxf[(i * 128 + t) * 2 + 1];
            ar += xr * wr - xi * wimag;
            ai += xr * wimag + xi * wr;
        }
        sof[t * 2 + 0] = ar; sof[t * 2 + 1] = ai;
    }
    __syncthreads();
    for (int task = t; task < 512; task += 256) {   // ifft along x (1/64)
        int xx = task >> 3, ky = task & 7;
        float ar = 0.f, ai = 0.f;
        for (int kxi = 0; kxi < 16; ++kxi) {
            int kx = (kxi < 8) ? kxi : (kxi - 16);
            float s, c;
            sincosf(2.f * PI_F * (float)(kx * xx) / 64.f, &s, &c);
            float vr = sof[(kxi * 8 + ky) * 2], vi = sof[(kxi * 8 + ky) * 2 + 1];
            ar += vr * c - vi * s;
            ai += vr * s + vi * c;
        }
        stt[(xx * 8 + ky) * 2 + 0] = ar * (1.f / 64.f);
        stt[(xx * 8 + ky) * 2 + 1] = ai * (1.f / 64.f);
    }
    __syncthreads();
    const float* wo = wpt + o * 32;
    float wb = wptb[o];
    for (int idx = t; idx < 4096; idx += 256) {
        int xx = idx >> 6, y = idx & 63;
        // irfft along y, n=64: DC imag dropped (C2R semantics), Nyquist zero
        float spec = stt[(xx * 8 + 0) * 2 + 0];
        #pragma unroll
        for (int ky = 1; ky < 8; ++ky)
            spec += 2.f * (stt[(xx * 8 + ky) * 2] * cy[ky * 64 + y]
                         - stt[(xx * 8 + ky) * 2 + 1] * sy[ky * 64 + y]);
        spec *= (1.f / 64.f);
        float pw = wb;
        for (int c = 0; c < 32; ++c)
            pw += wo[c] * h[((size_t)(b * 32 + c)) * 4096 + idx];
        float v = spec + pw;
        if (do_gelu) v = gelu_exact(v);
        hout[((size_t)(b * 32 + o)) * 4096 + idx] = v;
    }
}

// ---------------- centered 65x65 ortho-FFT modes: Fm(b,c,17,9) a=-8..8, b=-8..0 ----------------
__global__ __launch_bounds__(256) void k_nu_fm(const float* __restrict__ h, float* __restrict__ Fm)
{
    int bc = blockIdx.x;
    int t = threadIdx.x;
    __shared__ float sh[64 * 66];
    __shared__ float twc[9 * 64], tws[9 * 64];
    __shared__ float s1[64 * 9 * 2];
    const float* hp = h + (size_t)bc * 4096;
    for (int i = t; i < 4096; i += 256) sh[(i >> 6) * 66 + (i & 63)] = hp[i];
    for (int i = t; i < 9 * 64; i += 256) {
        int bbi = i >> 6, y = i & 63;
        float s, c;
        sincosf(-2.f * PI_F * (float)((bbi - 8) * y) / 65.f, &s, &c);
        twc[i] = c; tws[i] = s;
    }
    __syncthreads();
    for (int task = t; task < 64 * 9; task += 256) {
        int xx = task / 9, bbi = task % 9;
        float sr = 0.f, si = 0.f;
        const float* row = sh + xx * 66;
        const float* tc = twc + bbi * 64;
        const float* ts = tws + bbi * 64;
        for (int y = 0; y < 64; ++y) { sr += row[y] * tc[y]; si += row[y] * ts[y]; }
        s1[(xx * 9 + bbi) * 2 + 0] = sr;
        s1[(xx * 9 + bbi) * 2 + 1] = si;
    }
    __syncthreads();
    for (int task = t; task < 17 * 9; task += 256) {
        int ai2 = task / 9, bbi = task % 9;
        int afreq = ai2 - 8;
        float ar = 0.f, aim = 0.f;
        for (int xx = 0; xx < 64; ++xx) {
            float s, c;
            sincosf(-2.f * PI_F * (float)(afreq * xx) / 65.f, &s, &c);
            float vr = s1[(xx * 9 + bbi) * 2], vi = s1[(xx * 9 + bbi) * 2 + 1];
            ar += vr * c - vi * s;
            aim += vr * s + vi * c;
        }
        Fm[((size_t)bc * 153 + task) * 2 + 0] = ar * (1.f / 65.f);
        Fm[((size_t)bc * 153 + task) * 2 + 1] = aim * (1.f / 65.f);
    }
}

// ---------------- mode mix over channels + hermitian image assembly: images(b,s,17,17) ----------------
__global__ __launch_bounds__(256) void k_nu_img(
    const float* __restrict__ Fm, const float* __restrict__ nw1, const float* __restrict__ nw2,
    float* __restrict__ images)
{
    int blk = blockIdx.x;
    int b = blk >> 4, s = blk & 15;
    int t = threadIdx.x;
    __shared__ float im1[17 * 8 * 2];
    __shared__ float im2[9 * 2];
    if (t < 136) {
        int xx = t >> 3, y = t & 7;
        float ar = 0.f, ai = 0.f;
        for (int i = 0; i < 32; ++i) {
            size_t f0 = (((size_t)(b * 32 + i)) * 153 + xx * 9 + y) * 2;
            size_t w0 = (((size_t)(i * 16 + s) * 17 + xx) * 8 + y) * 2;
            float fr = Fm[f0], fi = Fm[f0 + 1];
            float wr = nw1[w0], wi = nw1[w0 + 1];
            ar += fr * wr - fi * wi;
            ai += fr * wi + fi * wr;
        }
        im1[t * 2] = ar; im1[t * 2 + 1] = ai;
    } else if (t < 145) {
        int k = t - 136;   // a = k-8, col b=0 (bbi=8)
        float ar = 0.f, ai = 0.f;
        for (int i = 0; i < 32; ++i) {
            size_t f0 = (((size_t)(b * 32 + i)) * 153 + k * 9 + 8) * 2;
            size_t w0 = ((size_t)(i * 16 + s) * 9 + k) * 2;
            float fr = Fm[f0], fi = Fm[f0 + 1];
            float wr = nw2[w0], wi = nw2[w0 + 1];
            ar += fr * wr - fi * wi;
            ai += fr * wi + fi * wr;
        }
        im2[k * 2] = ar; im2[k * 2 + 1] = ai;
    }
    __syncthreads();
    for (int task = t; task < 289; task += 256) {
        int xx = task / 17, y = task % 17;
        float vr, vi;
        if (y < 8)      { vr = im1[(xx * 8 + y) * 2];            vi = im1[(xx * 8 + y) * 2 + 1]; }
        else if (y > 8) { int sx = 16 - xx, sy2 = 16 - y;
                          vr = im1[(sx * 8 + sy2) * 2];          vi = -im1[(sx * 8 + sy2) * 2 + 1]; }
        else {
            if (xx < 8)       { vr = im2[xx * 2];        vi = im2[xx * 2 + 1]; }
            else if (xx == 8) { vr = im2[16];            vi = 0.f; }
            else              { vr = im2[(16 - xx) * 2]; vi = -im2[(16 - xx) * 2 + 1]; }
        }
        images[((size_t)blk * 289 + task) * 2 + 0] = vr;
        images[((size_t)blk * 289 + task) * 2 + 1] = vi;
    }
}

// ---------------- per-(b,s) bbox min/max over the subdomain's points ----------------
__global__ __launch_bounds__(256) void k_seg(
    const int* __restrict__ ind, const int* __restrict__ sep, const float* __restrict__ loc,
    float* __restrict__ mnmx)
{
    int blk = blockIdx.x;
    int b = blk >> 4, s = blk & 15;
    int t = threadIdx.x;
    int j0 = sep[b * 17 + s], j1 = sep[b * 17 + s + 1];
    float mn0 = 1e30f, mn1 = 1e30f, mx0 = -1e30f, mx1 = -1e30f;
    for (int j = j0 + t; j < j1; j += 256) {
        int p = ind[b * NYP + j];
        float l0 = loc[((size_t)b * NYP + p) * 2];
        float l1 = loc[((size_t)b * NYP + p) * 2 + 1];
        mn0 = fminf(mn0, l0); mx0 = fmaxf(mx0, l0);
        mn1 = fminf(mn1, l1); mx1 = fmaxf(mx1, l1);
    }
    __shared__ float r[4][256];
    r[0][t] = mn0; r[1][t] = mn1; r[2][t] = mx0; r[3][t] = mx1;
    __syncthreads();
    for (int st = 128; st > 0; st >>= 1) {
        if (t < st) {
            r[0][t] = fminf(r[0][t], r[0][t + st]);
            r[1][t] = fminf(r[1][t], r[1][t + st]);
            r[2][t] = fmaxf(r[2][t], r[2][t + st]);
            r[3][t] = fmaxf(r[3][t], r[3][t + st]);
        }
        __syncthreads();
    }
    if (t == 0) {
        mnmx[blk * 4 + 0] = r[0][0]; mnmx[blk * 4 + 1] = r[1][0];
        mnmx[blk * 4 + 2] = r[2][0]; mnmx[blk * 4 + 3] = r[3][0];
    }
}

// ---------------- exact type-2 NUDFT per point, only its own subdomain ----------------
__global__ __launch_bounds__(256) void k_nudft(
    const int* __restrict__ ind, const int* __restrict__ sep, const float* __restrict__ loc,
    const float* __restrict__ images, const float* __restrict__ mnmx,
    const float* __restrict__ nu_w, const float* __restrict__ nu_b,
    float* __restrict__ xnu)
{
    int blk = blockIdx.x;
    int b = blk >> 4, s = blk & 15;
    int t = threadIdx.x;
    __shared__ float img[289 * 2];
    for (int i = t; i < 578; i += 256) img[i] = images[(size_t)blk * 578 + i];
    __syncthreads();
    int j0 = sep[b * 17 + s], j1 = sep[b * 17 + s + 1];
    float mn0 = mnmx[blk * 4], mn1 = mnmx[blk * 4 + 1];
    float mx0 = mnmx[blk * 4 + 2], mx1 = mnmx[blk * 4 + 3];
    float nuw = nu_w[s], nub = nu_b[s];
    const float TWO_PI = 6.28318530717958647692f;
    for (int j = j0 + t; j < j1; j += 256) {
        int p = ind[b * NYP + j];
        float l0 = loc[((size_t)b * NYP + p) * 2];
        float l1 = loc[((size_t)b * NYP + p) * 2 + 1];
        float om0 = (l0 - mn0) / (mx0 - mn0 + 1e-6f) * TWO_PI - PI_F;
        float om1 = (l1 - mn1) / (mx1 - mn1 + 1e-6f) * TWO_PI - PI_F;
        float stepxs, stepxc, stepys, stepyc;
        sincosf(om0, &stepxs, &stepxc);
        sincosf(om1, &stepys, &stepyc);
        float ex_i, ex_r, ey0_i, ey0_r;
        sincosf(-8.f * om0, &ex_i, &ex_r);
        sincosf(-8.f * om1, &ey0_i, &ey0_r);
        float tot = 0.f;
        for (int xx = 0; xx < 17; ++xx) {
            float inr = 0.f, ini = 0.f;
            float eyr = ey0_r, eyi = ey0_i;
            const float* row = img + xx * 34;
            #pragma unroll
            for (int y = 0; y < 17; ++y) {
                float ir = row[y * 2], ii = row[y * 2 + 1];
                inr += ir * eyr - ii * eyi;
                ini += ir * eyi + ii * eyr;
                float nr = eyr * stepyc - eyi * stepys;
                eyi = eyr * stepys + eyi * stepyc;
                eyr = nr;
            }
            tot += ex_r * inr - ex_i * ini;
            float nr = ex_r * stepxc - ex_i * stepxs;
            ex_i = ex_r * stepxs + ex_i * stepxc;
            ex_r = nr;
        }
        xnu[(size_t)b * NYP + p] = (tot * (1.f / 17.f)) * nuw + nub;
    }
}

// ---------------- head MLP: q(b,g) = fc2(gelu(fc1(h[b,:,g]))) ----------------
__global__ __launch_bounds__(256) void k_head(
    const float* __restrict__ h, const float* __restrict__ Wfc1, const float* __restrict__ bfc1,
    const float* __restrict__ Wfc2, const float* __restrict__ bfc2, float* __restrict__ q)
{
    __shared__ float w1s[128 * 32];
    __shared__ float b1s[128];
    __shared__ float w2s[128];
    int t = threadIdx.x;
    for (int i = t; i < 4096; i += 256) w1s[i] = Wfc1[i];
    if (t < 128) { b1s[t] = bfc1[t]; w2s[t] = Wfc2[t]; }
    __syncthreads();
    int id = blockIdx.x * 256 + t;
    int b = id >> 12, g = id & 4095;
    float hv[32];
    #pragma unroll
    for (int c = 0; c < 32; ++c) hv[c] = h[((size_t)(b * 32 + c)) * GG + g];
    float acc = bfc2[0];
    for (int j = 0; j < 128; ++j) {
        float z = b1s[j];
        #pragma unroll
        for (int c = 0; c < 32; ++c) z += w1s[j * 32 + c] * hv[c];
        acc += w2s[j] * gelu_exact(z);
    }
    q[id] = acc;
}

// ---------------- de3 decoder + final combine with x_nu ----------------
// block handles 2 consecutive n rows; grid 4096 blocks for latency hiding headroom.
__global__ __launch_bounds__(256) void k_de3(
    const float* __restrict__ Wde3, const float* __restrict__ bde3,
    const float* __restrict__ q, const float* __restrict__ xnu, float* __restrict__ out)
{
    int nbase = blockIdx.x * 2;
    int t = threadIdx.x;
    float acc[8];
    #pragma unroll
    for (int k = 0; k < 8; ++k) acc[k] = 0.f;
    for (int g4 = t; g4 < GG / 4; g4 += 256) {
        float4 qb[4];
        #pragma unroll
        for (int b = 0; b < 4; ++b)
            qb[b] = ((const float4*)(q + (size_t)b * GG))[g4];
        #pragma unroll
        for (int r = 0; r < 2; ++r) {
            float4 w = ((const float4*)(Wde3 + (size_t)(nbase + r) * GG))[g4];
            #pragma unroll
            for (int b = 0; b < 4; ++b)
                acc[r * 4 + b] += w.x * qb[b].x + w.y * qb[b].y + w.z * qb[b].z + w.w * qb[b].w;
        }
    }
    #pragma unroll
    for (int k = 0; k < 8; ++k)
        for (int off = 32; off > 0; off >>= 1) acc[k] += __shfl_down(acc[k], off);
    __shared__ float red[4][8];
    int wave = t >> 6, lane = t & 63;
    if (lane == 0)
        for (int k = 0; k < 8; ++k) red[wave][k] = acc[k];
    __syncthreads();
    if (t < 8) {
        float v = red[0][t] + red[1][t] + red[2][t] + red[3][t];
        int r = t >> 2, b = t & 3;
        int n = nbase + r;
        out[(size_t)b * NYP + n] = v + bde3[n] + xnu[(size_t)b * NYP + n];
    }
}

extern "C" void kernel_launch(void* const* d_in, const int* in_sizes, int n_in,
                              void* d_out, int out_size, void* d_ws, size_t ws_size,
                              hipStream_t stream) {
    const float* x    = (const float*)d_in[0];
    const float* loc  = (const float*)d_in[1];
    const int*   ind  = (const int*)d_in[2];
    const int*   sep  = (const int*)d_in[3];
    const float* We1  = (const float*)d_in[4];
    const float* be1  = (const float*)d_in[5];
    const float* We2  = (const float*)d_in[6];
    const float* be2  = (const float*)d_in[7];
    const float* Wfc0 = (const float*)d_in[8];
    const float* bfc0 = (const float*)d_in[9];
    const float* cw1  = (const float*)d_in[10];
    const float* cw2  = (const float*)d_in[11];
    const float* wpt  = (const float*)d_in[12];
    const float* wptb = (const float*)d_in[13];
    const float* nw1  = (const float*)d_in[14];
    const float* nw2  = (const float*)d_in[15];
    const float* nuw  = (const float*)d_in[16];
    const float* nub  = (const float*)d_in[17];
    const float* Wde3 = (const float*)d_in[18];
    const float* bde3 = (const float*)d_in[19];
    const float* Wfc1 = (const float*)d_in[20];
    const float* bfc1 = (const float*)d_in[21];
    const float* Wfc2 = (const float*)d_in[22];
    const float* bfc2 = (const float*)d_in[23];
    float* out = (float*)d_out;

    float* ws     = (float*)d_ws;
    float* hA     = ws;                                   // B*32*G = 524288
    float* hB     = hA + (size_t)BB * WIDTH * GG;         // 524288
    float* xfbuf  = hB + (size_t)BB * WIDTH * GG;         // B*32*128*2 = 65536
    float* Fm     = xfbuf + (size_t)BB * WIDTH * 128 * 2; // B*32*153*2 = 39168
    float* images = Fm + (size_t)BB * WIDTH * 153 * 2;    // B*S*289*2 = 36992
    float* mnmx   = images + (size_t)BB * SS * 289 * 2;   // 256
    float* q      = mnmx + 256;                           // B*G = 16384
    float* xnu    = q + (size_t)BB * GG;                  // B*NY = 32768

    k_seg<<<BB * SS, 256, 0, stream>>>(ind, sep, loc, mnmx);
    k_embed<<<GG / 2, 256, 0, stream>>>(x, loc, We1, be1, We2, be2, Wfc0, bfc0, hA);

    const float* hin = hA;
    float* hout = hB;
    for (int l = 0; l < 4; ++l) {
        k_xf<<<BB * WIDTH, 256, 0, stream>>>(hin, xfbuf);
        k_mix_inv<<<BB * WIDTH, 256, 0, stream>>>(hin, xfbuf,
                                                  cw1 + (size_t)l * 16384, cw2 + (size_t)l * 16384,
                                                  wpt + l * 1024, wptb + l * 32,
                                                  hout, (l < 3) ? 1 : 0);
        float* tmp = (float*)hin; hin = hout; hout = tmp;
    }
    // hin now = hA = final trunk activation
    k_nu_fm<<<BB * WIDTH, 256, 0, stream>>>(hin, Fm);
    k_nu_img<<<BB * SS, 256, 0, stream>>>(Fm, nw1, nw2, images);
    k_nudft<<<BB * SS, 256, 0, stream>>>(ind, sep, loc, images, mnmx, nuw, nub, xnu);
    k_head<<<(BB * GG) / 256, 256, 0, stream>>>(hin, Wfc1, bfc1, Wfc2, bfc2, q);
    k_de3<<<NYP / 2, 256, 0, stream>>>(Wde3, bde3, q, xnu, out);
}

// Round 3
// 788.089 us; speedup vs baseline: 1.0146x; 1.0146x over previous
//
#include <hip/hip_runtime.h>
#include <math.h>

#define BB 4
#define NX 4096
#define NYP 8192
#define GG 4096
#define WIDTH 32
#define SS 16
#define PI_F 3.14159265358979323846f

__device__ __forceinline__ float gelu_exact(float v) {
    return 0.5f * v * (1.0f + erff(v * 0.70710678118654752f));
}

// ---------------- embed (2 matvec families) + fc0 -> h0 (B,32,64,64) ----------------
// block handles 8 consecutive g rows (grid 512): amortizes the 320KB broadcast
// (x+loc) over 8 weight rows, and gives 8 independent weight loads in flight.
__global__ __launch_bounds__(256, 2) void k_embed(
    const float* __restrict__ x, const float* __restrict__ loc,
    const float* __restrict__ We1, const float* __restrict__ be1,
    const float* __restrict__ We2, const float* __restrict__ be2,
    const float* __restrict__ Wfc0, const float* __restrict__ bfc0,
    float* __restrict__ h0)
{
    int gbase = blockIdx.x * 8;
    int t = threadIdx.x;

    // ---- x family: accx[r*4+b]
    float accx[32];
    #pragma unroll
    for (int k = 0; k < 32; ++k) accx[k] = 0.f;
    for (int n4 = t; n4 < NX / 4; n4 += 256) {     // 4 iterations
        float4 xb[4];
        #pragma unroll
        for (int b = 0; b < 4; ++b)
            xb[b] = ((const float4*)(x + (size_t)b * NX))[n4];
        float4 w[8];
        #pragma unroll
        for (int r = 0; r < 8; ++r)
            w[r] = ((const float4*)(We1 + (size_t)(gbase + r) * NX))[n4];
        #pragma unroll
        for (int r = 0; r < 8; ++r)
            #pragma unroll
            for (int b = 0; b < 4; ++b)
                accx[r * 4 + b] += w[r].x * xb[b].x + w[r].y * xb[b].y
                                 + w[r].z * xb[b].z + w[r].w * xb[b].w;
    }

    // ---- loc family: accl[ch*32 + r*4 + b]
    float accl[64];
    #pragma unroll
    for (int k = 0; k < 64; ++k) accl[k] = 0.f;
    for (int n4 = t; n4 < NYP / 4; n4 += 256) {    // 8 iterations
        float4 p0[4], p1[4];
        #pragma unroll
        for (int b = 0; b < 4; ++b) {
            const float4* lb = (const float4*)(loc + (size_t)b * NYP * 2);
            p0[b] = lb[n4 * 2];
            p1[b] = lb[n4 * 2 + 1];
        }
        float4 w[8];
        #pragma unroll
        for (int r = 0; r < 8; ++r)
            w[r] = ((const float4*)(We2 + (size_t)(gbase + r) * NYP))[n4];
        #pragma unroll
        for (int r = 0; r < 8; ++r)
            #pragma unroll
            for (int b = 0; b < 4; ++b) {
                accl[r * 4 + b]      += w[r].x * p0[b].x + w[r].y * p0[b].z
                                      + w[r].z * p1[b].x + w[r].w * p1[b].z;
                accl[32 + r * 4 + b] += w[r].x * p0[b].y + w[r].y * p0[b].w
                                      + w[r].z * p1[b].y + w[r].w * p1[b].w;
            }
    }

    // wave reduce then cross-wave
    #pragma unroll
    for (int k = 0; k < 32; ++k)
        for (int off = 32; off > 0; off >>= 1) accx[k] += __shfl_down(accx[k], off);
    #pragma unroll
    for (int k = 0; k < 64; ++k)
        for (int off = 32; off > 0; off >>= 1) accl[k] += __shfl_down(accl[k], off);
    __shared__ float red[4][96];
    __shared__ float tot[96];
    int wave = t >> 6, lane = t & 63;
    if (lane == 0) {
        for (int k = 0; k < 32; ++k) red[wave][k] = accx[k];
        for (int k = 0; k < 64; ++k) red[wave][32 + k] = accl[k];
    }
    __syncthreads();
    if (t < 96) tot[t] = red[0][t] + red[1][t] + red[2][t] + red[3][t];
    __syncthreads();
    if (t < 128) {
        int b = t >> 5, w = t & 31;
        float w0 = Wfc0[w * 3 + 0], w1c = Wfc0[w * 3 + 1], w2c = Wfc0[w * 3 + 2], bb0 = bfc0[w];
        #pragma unroll
        for (int r = 0; r < 8; ++r) {
            int g = gbase + r;
            float xe = tot[r * 4 + b] + be1[g];
            float l0 = tot[32 + r * 4 + b] + be2[g];
            float l1 = tot[64 + r * 4 + b] + be2[g];
            h0[((size_t)(b * WIDTH + w)) * GG + g] = xe * w0 + l0 * w1c + l1 * w2c + bb0;
        }
    }
}

// ---------------- truncated forward DFT: h(b,c,64,64) -> xf(b,c,16,8) complex ----------------
__global__ __launch_bounds__(256) void k_xf(const float* __restrict__ h, float* __restrict__ xf)
{
    int bc = blockIdx.x;
    int t = threadIdx.x;
    __shared__ float sh[64 * 66];          // padded rows: bank-conflict-free stage-1
    __shared__ float twc[8 * 64], tws[8 * 64];
    __shared__ float s1[64 * 8 * 2];
    const float* hp = h + (size_t)bc * 4096;
    for (int i = t; i < 4096; i += 256) sh[(i >> 6) * 66 + (i & 63)] = hp[i];
    for (int i = t; i < 512; i += 256) {
        int ky = i >> 6, y = i & 63;
        float s, c;
        sincosf(-2.f * PI_F * (float)(ky * y) / 64.f, &s, &c);
        twc[i] = c; tws[i] = s;
    }
    __syncthreads();
    for (int task = t; task < 512; task += 256) {
        int xx = task >> 3, ky = task & 7;
        float sr = 0.f, si = 0.f;
        const float* row = sh + xx * 66;
        const float* tc = twc + ky * 64;
        const float* ts = tws + ky * 64;
        for (int y = 0; y < 64; ++y) { sr += row[y] * tc[y]; si += row[y] * ts[y]; }
        s1[(xx * 8 + ky) * 2 + 0] = sr;
        s1[(xx * 8 + ky) * 2 + 1] = si;
    }
    __syncthreads();
    if (t < 128) {
        int kxi = t >> 3, ky = t & 7;
        int kx = (kxi < 8) ? kxi : (kxi - 16);   // negative freq alias of rows 56..63
        float ar = 0.f, ai = 0.f;
        for (int xx = 0; xx < 64; ++xx) {
            float s, c;
            sincosf(-2.f * PI_F * (float)(kx * xx) / 64.f, &s, &c);
            float vr = s1[(xx * 8 + ky) * 2], vi = s1[(xx * 8 + ky) * 2 + 1];
            ar += vr * c - vi * s;
            ai += vr * s + vi * c;
        }
        xf[((size_t)bc * 128 + t) * 2 + 0] = ar;
        xf[((size_t)bc * 128 + t) * 2 + 1] = ai;
    }
}

// ---------------- mode mix + truncated inverse DFT + pointwise + gelu ----------------
__global__ __launch_bounds__(256) void k_mix_inv(
    const float* __restrict__ h, const float* __restrict__ xf,
    const float* __restrict__ w1, const float* __restrict__ w2,
    const float* __restrict__ wpt, const float* __restrict__ wptb,
    float* __restrict__ hout, int do_gelu)
{
    int blk = blockIdx.x;
    int b = blk >> 5, o = blk & 31;
    int t = threadIdx.x;
    __shared__ float sxf[32 * 128 * 2];   // 32 KB
    __shared__ float sof[128 * 2];
    __shared__ float stt[64 * 8 * 2];
    __shared__ float cy[8 * 64], sy[8 * 64];
    const float* xfb = xf + (size_t)b * 32 * 128 * 2;
    for (int i = t; i < 32 * 128 * 2; i += 256) sxf[i] = xfb[i];
    for (int i = t; i < 512; i += 256) {
        int ky = i >> 6, y = i & 63;
        float s, c;
        sincosf(2.f * PI_F * (float)(ky * y) / 64.f, &s, &c);
        cy[i] = c; sy[i] = s;
    }
    __syncthreads();
    if (t < 128) {                          // of[o] = sum_i xf[i] * w[i,o]
        int kxi = t >> 3, ky = t & 7;
        const float* w = (kxi < 8) ? w1 : w2;
        int kxw = kxi & 7;
        float ar = 0.f, ai = 0.f;
        for (int i = 0; i < 32; ++i) {
            size_t wi0 = (((size_t)(i * 32 + o) * 8 + kxw) * 8 + ky) * 2;
            float wr = w[wi0], wimag = w[wi0 + 1];
            float xr = sxf[(i * 128 + t) * 2], xi = sxf[(i * 128 + t) * 2 + 1];
            ar += xr * wr - xi * wimag;
            ai += xr * wimag + xi * wr;
        }
        sof[t * 2 + 0] = ar; sof[t * 2 + 1] = ai;
    }
    __syncthreads();
    for (int task = t; task < 512; task += 256) {   // ifft along x (1/64)
        int xx = task >> 3, ky = task & 7;
        float ar = 0.f, ai = 0.f;
        for (int kxi = 0; kxi < 16; ++kxi) {
            int kx = (kxi < 8) ? kxi : (kxi - 16);
            float s, c;
            sincosf(2.f * PI_F * (float)(kx * xx) / 64.f, &s, &c);
            float vr = sof[(kxi * 8 + ky) * 2], vi = sof[(kxi * 8 + ky) * 2 + 1];
            ar += vr * c - vi * s;
            ai += vr * s + vi * c;
        }
        stt[(xx * 8 + ky) * 2 + 0] = ar * (1.f / 64.f);
        stt[(xx * 8 + ky) * 2 + 1] = ai * (1.f / 64.f);
    }
    __syncthreads();
    const float* wo = wpt + o * 32;
    float wb = wptb[o];
    for (int idx = t; idx < 4096; idx += 256) {
        int xx = idx >> 6, y = idx & 63;
        // irfft along y, n=64: DC imag dropped (C2R semantics), Nyquist zero
        float spec = stt[(xx * 8 + 0) * 2 + 0];
        #pragma unroll
        for (int ky = 1; ky < 8; ++ky)
            spec += 2.f * (stt[(xx * 8 + ky) * 2] * cy[ky * 64 + y]
                         - stt[(xx * 8 + ky) * 2 + 1] * sy[ky * 64 + y]);
        spec *= (1.f / 64.f);
        float pw = wb;
        for (int c = 0; c < 32; ++c)
            pw += wo[c] * h[((size_t)(b * 32 + c)) * 4096 + idx];
        float v = spec + pw;
        if (do_gelu) v = gelu_exact(v);
        hout[((size_t)(b * 32 + o)) * 4096 + idx] = v;
    }
}

// ---------------- centered 65x65 ortho-FFT modes: Fm(b,c,17,9) a=-8..8, b=-8..0 ----------------
__global__ __launch_bounds__(256) void k_nu_fm(const float* __restrict__ h, float* __restrict__ Fm)
{
    int bc = blockIdx.x;
    int t = threadIdx.x;
    __shared__ float sh[64 * 66];
    __shared__ float twc[9 * 64], tws[9 * 64];
    __shared__ float s1[64 * 9 * 2];
    const float* hp = h + (size_t)bc * 4096;
    for (int i = t; i < 4096; i += 256) sh[(i >> 6) * 66 + (i & 63)] = hp[i];
    for (int i = t; i < 9 * 64; i += 256) {
        int bbi = i >> 6, y = i & 63;
        float s, c;
        sincosf(-2.f * PI_F * (float)((bbi - 8) * y) / 65.f, &s, &c);
        twc[i] = c; tws[i] = s;
    }
    __syncthreads();
    for (int task = t; task < 64 * 9; task += 256) {
        int xx = task / 9, bbi = task % 9;
        float sr = 0.f, si = 0.f;
        const float* row = sh + xx * 66;
        const float* tc = twc + bbi * 64;
        const float* ts = tws + bbi * 64;
        for (int y = 0; y < 64; ++y) { sr += row[y] * tc[y]; si += row[y] * ts[y]; }
        s1[(xx * 9 + bbi) * 2 + 0] = sr;
        s1[(xx * 9 + bbi) * 2 + 1] = si;
    }
    __syncthreads();
    for (int task = t; task < 17 * 9; task += 256) {
        int ai2 = task / 9, bbi = task % 9;
        int afreq = ai2 - 8;
        float ar = 0.f, aim = 0.f;
        for (int xx = 0; xx < 64; ++xx) {
            float s, c;
            sincosf(-2.f * PI_F * (float)(afreq * xx) / 65.f, &s, &c);
            float vr = s1[(xx * 9 + bbi) * 2], vi = s1[(xx * 9 + bbi) * 2 + 1];
            ar += vr * c - vi * s;
            aim += vr * s + vi * c;
        }
        Fm[((size_t)bc * 153 + task) * 2 + 0] = ar * (1.f / 65.f);
        Fm[((size_t)bc * 153 + task) * 2 + 1] = aim * (1.f / 65.f);
    }
}

// ---------------- mode mix over channels + hermitian image assembly: images(b,s,17,17) ----------------
__global__ __launch_bounds__(256) void k_nu_img(
    const float* __restrict__ Fm, const float* __restrict__ nw1, const float* __restrict__ nw2,
    float* __restrict__ images)
{
    int blk = blockIdx.x;
    int b = blk >> 4, s = blk & 15;
    int t = threadIdx.x;
    __shared__ float im1[17 * 8 * 2];
    __shared__ float im2[9 * 2];
    if (t < 136) {
        int xx = t >> 3, y = t & 7;
        float ar = 0.f, ai = 0.f;
        for (int i = 0; i < 32; ++i) {
            size_t f0 = (((size_t)(b * 32 + i)) * 153 + xx * 9 + y) * 2;
            size_t w0 = (((size_t)(i * 16 + s) * 17 + xx) * 8 + y) * 2;
            float fr = Fm[f0], fi = Fm[f0 + 1];
            float wr = nw1[w0], wi = nw1[w0 + 1];
            ar += fr * wr - fi * wi;
            ai += fr * wi + fi * wr;
        }
        im1[t * 2] = ar; im1[t * 2 + 1] = ai;
    } else if (t < 145) {
        int k = t - 136;   // a = k-8, col b=0 (bbi=8)
        float ar = 0.f, ai = 0.f;
        for (int i = 0; i < 32; ++i) {
            size_t f0 = (((size_t)(b * 32 + i)) * 153 + k * 9 + 8) * 2;
            size_t w0 = ((size_t)(i * 16 + s) * 9 + k) * 2;
            float fr = Fm[f0], fi = Fm[f0 + 1];
            float wr = nw2[w0], wi = nw2[w0 + 1];
            ar += fr * wr - fi * wi;
            ai += fr * wi + fi * wr;
        }
        im2[k * 2] = ar; im2[k * 2 + 1] = ai;
    }
    __syncthreads();
    for (int task = t; task < 289; task += 256) {
        int xx = task / 17, y = task % 17;
        float vr, vi;
        if (y < 8)      { vr = im1[(xx * 8 + y) * 2];            vi = im1[(xx * 8 + y) * 2 + 1]; }
        else if (y > 8) { int sx = 16 - xx, sy2 = 16 - y;
                          vr = im1[(sx * 8 + sy2) * 2];          vi = -im1[(sx * 8 + sy2) * 2 + 1]; }
        else {
            if (xx < 8)       { vr = im2[xx * 2];        vi = im2[xx * 2 + 1]; }
            else if (xx == 8) { vr = im2[16];            vi = 0.f; }
            else              { vr = im2[(16 - xx) * 2]; vi = -im2[(16 - xx) * 2 + 1]; }
        }
        images[((size_t)blk * 289 + task) * 2 + 0] = vr;
        images[((size_t)blk * 289 + task) * 2 + 1] = vi;
    }
}

// ---------------- per-(b,s) bbox min/max over the subdomain's points ----------------
__global__ __launch_bounds__(256) void k_seg(
    const int* __restrict__ ind, const int* __restrict__ sep, const float* __restrict__ loc,
    float* __restrict__ mnmx)
{
    int blk = blockIdx.x;
    int b = blk >> 4, s = blk & 15;
    int t = threadIdx.x;
    int j0 = sep[b * 17 + s], j1 = sep[b * 17 + s + 1];
    float mn0 = 1e30f, mn1 = 1e30f, mx0 = -1e30f, mx1 = -1e30f;
    for (int j = j0 + t; j < j1; j += 256) {
        int p = ind[b * NYP + j];
        float l0 = loc[((size_t)b * NYP + p) * 2];
        float l1 = loc[((size_t)b * NYP + p) * 2 + 1];
        mn0 = fminf(mn0, l0); mx0 = fmaxf(mx0, l0);
        mn1 = fminf(mn1, l1); mx1 = fmaxf(mx1, l1);
    }
    __shared__ float r[4][256];
    r[0][t] = mn0; r[1][t] = mn1; r[2][t] = mx0; r[3][t] = mx1;
    __syncthreads();
    for (int st = 128; st > 0; st >>= 1) {
        if (t < st) {
            r[0][t] = fminf(r[0][t], r[0][t + st]);
            r[1][t] = fminf(r[1][t], r[1][t + st]);
            r[2][t] = fmaxf(r[2][t], r[2][t + st]);
            r[3][t] = fmaxf(r[3][t], r[3][t + st]);
        }
        __syncthreads();
    }
    if (t == 0) {
        mnmx[blk * 4 + 0] = r[0][0]; mnmx[blk * 4 + 1] = r[1][0];
        mnmx[blk * 4 + 2] = r[2][0]; mnmx[blk * 4 + 3] = r[3][0];
    }
}

// ---------------- exact type-2 NUDFT per point, only its own subdomain ----------------
__global__ __launch_bounds__(256) void k_nudft(
    const int* __restrict__ ind, const int* __restrict__ sep, const float* __restrict__ loc,
    const float* __restrict__ images, const float* __restrict__ mnmx,
    const float* __restrict__ nu_w, const float* __restrict__ nu_b,
    float* __restrict__ xnu)
{
    int blk = blockIdx.x;
    int b = blk >> 4, s = blk & 15;
    int t = threadIdx.x;
    __shared__ float img[289 * 2];
    for (int i = t; i < 578; i += 256) img[i] = images[(size_t)blk * 578 + i];
    __syncthreads();
    int j0 = sep[b * 17 + s], j1 = sep[b * 17 + s + 1];
    float mn0 = mnmx[blk * 4], mn1 = mnmx[blk * 4 + 1];
    float mx0 = mnmx[blk * 4 + 2], mx1 = mnmx[blk * 4 + 3];
    float nuw = nu_w[s], nub = nu_b[s];
    const float TWO_PI = 6.28318530717958647692f;
    for (int j = j0 + t; j < j1; j += 256) {
        int p = ind[b * NYP + j];
        float l0 = loc[((size_t)b * NYP + p) * 2];
        float l1 = loc[((size_t)b * NYP + p) * 2 + 1];
        float om0 = (l0 - mn0) / (mx0 - mn0 + 1e-6f) * TWO_PI - PI_F;
        float om1 = (l1 - mn1) / (mx1 - mn1 + 1e-6f) * TWO_PI - PI_F;
        float stepxs, stepxc, stepys, stepyc;
        sincosf(om0, &stepxs, &stepxc);
        sincosf(om1, &stepys, &stepyc);
        float ex_i, ex_r, ey0_i, ey0_r;
        sincosf(-8.f * om0, &ex_i, &ex_r);
        sincosf(-8.f * om1, &ey0_i, &ey0_r);
        float tot = 0.f;
        for (int xx = 0; xx < 17; ++xx) {
            float inr = 0.f, ini = 0.f;
            float eyr = ey0_r, eyi = ey0_i;
            const float* row = img + xx * 34;
            #pragma unroll
            for (int y = 0; y < 17; ++y) {
                float ir = row[y * 2], ii = row[y * 2 + 1];
                inr += ir * eyr - ii * eyi;
                ini += ir * eyi + ii * eyr;
                float nr = eyr * stepyc - eyi * stepys;
                eyi = eyr * stepys + eyi * stepyc;
                eyr = nr;
            }
            tot += ex_r * inr - ex_i * ini;
            float nr = ex_r * stepxc - ex_i * stepxs;
            ex_i = ex_r * stepxs + ex_i * stepxc;
            ex_r = nr;
        }
        xnu[(size_t)b * NYP + p] = (tot * (1.f / 17.f)) * nuw + nub;
    }
}

// ---------------- head MLP: q(b,g) = fc2(gelu(fc1(h[b,:,g]))) ----------------
__global__ __launch_bounds__(256) void k_head(
    const float* __restrict__ h, const float* __restrict__ Wfc1, const float* __restrict__ bfc1,
    const float* __restrict__ Wfc2, const float* __restrict__ bfc2, float* __restrict__ q)
{
    __shared__ float w1s[128 * 32];
    __shared__ float b1s[128];
    __shared__ float w2s[128];
    int t = threadIdx.x;
    for (int i = t; i < 4096; i += 256) w1s[i] = Wfc1[i];
    if (t < 128) { b1s[t] = bfc1[t]; w2s[t] = Wfc2[t]; }
    __syncthreads();
    int id = blockIdx.x * 256 + t;
    int b = id >> 12, g = id & 4095;
    float hv[32];
    #pragma unroll
    for (int c = 0; c < 32; ++c) hv[c] = h[((size_t)(b * 32 + c)) * GG + g];
    float acc = bfc2[0];
    for (int j = 0; j < 128; ++j) {
        float z = b1s[j];
        #pragma unroll
        for (int c = 0; c < 32; ++c) z += w1s[j * 32 + c] * hv[c];
        acc += w2s[j] * gelu_exact(z);
    }
    q[id] = acc;
}

// ---------------- de3 decoder + final combine with x_nu ----------------
// block handles 8 consecutive n rows (grid 1024): amortizes the 64KB q broadcast
// over 128KB of unique Wde3 rows, 8 weight streams in flight.
__global__ __launch_bounds__(256) void k_de3(
    const float* __restrict__ Wde3, const float* __restrict__ bde3,
    const float* __restrict__ q, const float* __restrict__ xnu, float* __restrict__ out)
{
    int nbase = blockIdx.x * 8;
    int t = threadIdx.x;
    float acc[32];
    #pragma unroll
    for (int k = 0; k < 32; ++k) acc[k] = 0.f;
    for (int g4 = t; g4 < GG / 4; g4 += 256) {     // 4 iterations
        float4 qb[4];
        #pragma unroll
        for (int b = 0; b < 4; ++b)
            qb[b] = ((const float4*)(q + (size_t)b * GG))[g4];
        float4 w[8];
        #pragma unroll
        for (int r = 0; r < 8; ++r)
            w[r] = ((const float4*)(Wde3 + (size_t)(nbase + r) * GG))[g4];
        #pragma unroll
        for (int r = 0; r < 8; ++r)
            #pragma unroll
            for (int b = 0; b < 4; ++b)
                acc[r * 4 + b] += w[r].x * qb[b].x + w[r].y * qb[b].y
                                + w[r].z * qb[b].z + w[r].w * qb[b].w;
    }
    #pragma unroll
    for (int k = 0; k < 32; ++k)
        for (int off = 32; off > 0; off >>= 1) acc[k] += __shfl_down(acc[k], off);
    __shared__ float red[4][32];
    int wave = t >> 6, lane = t & 63;
    if (lane == 0)
        for (int k = 0; k < 32; ++k) red[wave][k] = acc[k];
    __syncthreads();
    if (t < 32) {
        float v = red[0][t] + red[1][t] + red[2][t] + red[3][t];
        int r = t >> 2, b = t & 3;
        int n = nbase + r;
        out[(size_t)b * NYP + n] = v + bde3[n] + xnu[(size_t)b * NYP + n];
    }
}

extern "C" void kernel_launch(void* const* d_in, const int* in_sizes, int n_in,
                              void* d_out, int out_size, void* d_ws, size_t ws_size,
                              hipStream_t stream) {
    const float* x    = (const float*)d_in[0];
    const float* loc  = (const float*)d_in[1];
    const int*   ind  = (const int*)d_in[2];
    const int*   sep  = (const int*)d_in[3];
    const float* We1  = (const float*)d_in[4];
    const float* be1  = (const float*)d_in[5];
    const float* We2  = (const float*)d_in[6];
    const float* be2  = (const float*)d_in[7];
    const float* Wfc0 = (const float*)d_in[8];
    const float* bfc0 = (const float*)d_in[9];
    const float* cw1  = (const float*)d_in[10];
    const float* cw2  = (const float*)d_in[11];
    const float* wpt  = (const float*)d_in[12];
    const float* wptb = (const float*)d_in[13];
    const float* nw1  = (const float*)d_in[14];
    const float* nw2  = (const float*)d_in[15];
    const float* nuw  = (const float*)d_in[16];
    const float* nub  = (const float*)d_in[17];
    const float* Wde3 = (const float*)d_in[18];
    const float* bde3 = (const float*)d_in[19];
    const float* Wfc1 = (const float*)d_in[20];
    const float* bfc1 = (const float*)d_in[21];
    const float* Wfc2 = (const float*)d_in[22];
    const float* bfc2 = (const float*)d_in[23];
    float* out = (float*)d_out;

    float* ws     = (float*)d_ws;
    float* hA     = ws;                                   // B*32*G = 524288
    float* hB     = hA + (size_t)BB * WIDTH * GG;         // 524288
    float* xfbuf  = hB + (size_t)BB * WIDTH * GG;         // B*32*128*2 = 65536
    float* Fm     = xfbuf + (size_t)BB * WIDTH * 128 * 2; // B*32*153*2 = 39168
    float* images = Fm + (size_t)BB * WIDTH * 153 * 2;    // B*S*289*2 = 36992
    float* mnmx   = images + (size_t)BB * SS * 289 * 2;   // 256
    float* q      = mnmx + 256;                           // B*G = 16384
    float* xnu    = q + (size_t)BB * GG;                  // B*NY = 32768

    k_seg<<<BB * SS, 256, 0, stream>>>(ind, sep, loc, mnmx);
    k_embed<<<GG / 8, 256, 0, stream>>>(x, loc, We1, be1, We2, be2, Wfc0, bfc0, hA);

    const float* hin = hA;
    float* hout = hB;
    for (int l = 0; l < 4; ++l) {
        k_xf<<<BB * WIDTH, 256, 0, stream>>>(hin, xfbuf);
        k_mix_inv<<<BB * WIDTH, 256, 0, stream>>>(hin, xfbuf,
                                                  cw1 + (size_t)l * 16384, cw2 + (size_t)l * 16384,
                                                  wpt + l * 1024, wptb + l * 32,
                                                  hout, (l < 3) ? 1 : 0);
        float* tmp = (float*)hin; hin = hout; hout = tmp;
    }
    // hin now = hA = final trunk activation
    k_nu_fm<<<BB * WIDTH, 256, 0, stream>>>(hin, Fm);
    k_nu_img<<<BB * SS, 256, 0, stream>>>(Fm, nw1, nw2, images);
    k_nudft<<<BB * SS, 256, 0, stream>>>(ind, sep, loc, images, mnmx, nuw, nub, xnu);
    k_head<<<(BB * GG) / 256, 256, 0, stream>>>(hin, Wfc1, bfc1, Wfc2, bfc2, q);
    k_de3<<<NYP / 8, 256, 0, stream>>>(Wde3, bde3, q, xnu, out);
}

// Round 4
// 600.367 us; speedup vs baseline: 1.3318x; 1.3127x over previous
//
#include <hip/hip_runtime.h>
#include <math.h>

#define BB 4
#define NX 4096
#define NYP 8192
#define GG 4096
#define WIDTH 32
#define SS 16
#define PI_F 3.14159265358979323846f

__device__ __forceinline__ float gelu_exact(float v) {
    return 0.5f * v * (1.0f + erff(v * 0.70710678118654752f));
}

// ---------------- embed (2 matvec families) + fc0 -> h0 (B,32,64,64) ----------------
// PARKED: r=2/4/8 all ~89us, FETCH invariant ~100MB @1.17TB/s -> not partition-limited.
__global__ __launch_bounds__(256, 2) void k_embed(
    const float* __restrict__ x, const float* __restrict__ loc,
    const float* __restrict__ We1, const float* __restrict__ be1,
    const float* __restrict__ We2, const float* __restrict__ be2,
    const float* __restrict__ Wfc0, const float* __restrict__ bfc0,
    float* __restrict__ h0)
{
    int gbase = blockIdx.x * 8;
    int t = threadIdx.x;

    float accx[32];
    #pragma unroll
    for (int k = 0; k < 32; ++k) accx[k] = 0.f;
    for (int n4 = t; n4 < NX / 4; n4 += 256) {
        float4 xb[4];
        #pragma unroll
        for (int b = 0; b < 4; ++b)
            xb[b] = ((const float4*)(x + (size_t)b * NX))[n4];
        float4 w[8];
        #pragma unroll
        for (int r = 0; r < 8; ++r)
            w[r] = ((const float4*)(We1 + (size_t)(gbase + r) * NX))[n4];
        #pragma unroll
        for (int r = 0; r < 8; ++r)
            #pragma unroll
            for (int b = 0; b < 4; ++b)
                accx[r * 4 + b] += w[r].x * xb[b].x + w[r].y * xb[b].y
                                 + w[r].z * xb[b].z + w[r].w * xb[b].w;
    }

    float accl[64];
    #pragma unroll
    for (int k = 0; k < 64; ++k) accl[k] = 0.f;
    for (int n4 = t; n4 < NYP / 4; n4 += 256) {
        float4 p0[4], p1[4];
        #pragma unroll
        for (int b = 0; b < 4; ++b) {
            const float4* lb = (const float4*)(loc + (size_t)b * NYP * 2);
            p0[b] = lb[n4 * 2];
            p1[b] = lb[n4 * 2 + 1];
        }
        float4 w[8];
        #pragma unroll
        for (int r = 0; r < 8; ++r)
            w[r] = ((const float4*)(We2 + (size_t)(gbase + r) * NYP))[n4];
        #pragma unroll
        for (int r = 0; r < 8; ++r)
            #pragma unroll
            for (int b = 0; b < 4; ++b) {
                accl[r * 4 + b]      += w[r].x * p0[b].x + w[r].y * p0[b].z
                                      + w[r].z * p1[b].x + w[r].w * p1[b].z;
                accl[32 + r * 4 + b] += w[r].x * p0[b].y + w[r].y * p0[b].w
                                      + w[r].z * p1[b].y + w[r].w * p1[b].w;
            }
    }

    #pragma unroll
    for (int k = 0; k < 32; ++k)
        for (int off = 32; off > 0; off >>= 1) accx[k] += __shfl_down(accx[k], off);
    #pragma unroll
    for (int k = 0; k < 64; ++k)
        for (int off = 32; off > 0; off >>= 1) accl[k] += __shfl_down(accl[k], off);
    __shared__ float red[4][96];
    __shared__ float tot[96];
    int wave = t >> 6, lane = t & 63;
    if (lane == 0) {
        for (int k = 0; k < 32; ++k) red[wave][k] = accx[k];
        for (int k = 0; k < 64; ++k) red[wave][32 + k] = accl[k];
    }
    __syncthreads();
    if (t < 96) tot[t] = red[0][t] + red[1][t] + red[2][t] + red[3][t];
    __syncthreads();
    if (t < 128) {
        int b = t >> 5, w = t & 31;
        float w0 = Wfc0[w * 3 + 0], w1c = Wfc0[w * 3 + 1], w2c = Wfc0[w * 3 + 2], bb0 = bfc0[w];
        #pragma unroll
        for (int r = 0; r < 8; ++r) {
            int g = gbase + r;
            float xe = tot[r * 4 + b] + be1[g];
            float l0 = tot[32 + r * 4 + b] + be2[g];
            float l1 = tot[64 + r * 4 + b] + be2[g];
            h0[((size_t)(b * WIDTH + w)) * GG + g] = xe * w0 + l0 * w1c + l1 * w2c + bb0;
        }
    }
}

// ---------------- truncated forward DFT: h(b,c,64,64) -> xf(b,c,16,8) complex ----------------
__global__ __launch_bounds__(256) void k_xf(const float* __restrict__ h, float* __restrict__ xf)
{
    int bc = blockIdx.x;
    int t = threadIdx.x;
    __shared__ float sh[64 * 66];          // padded rows: bank-conflict-free stage-1
    __shared__ float twc[8 * 64], tws[8 * 64];
    __shared__ float s1[64 * 8 * 2];
    const float* hp = h + (size_t)bc * 4096;
    for (int i = t; i < 4096; i += 256) sh[(i >> 6) * 66 + (i & 63)] = hp[i];
    for (int i = t; i < 512; i += 256) {
        int ky = i >> 6, y = i & 63;
        float s, c;
        sincosf(-2.f * PI_F * (float)(ky * y) / 64.f, &s, &c);
        twc[i] = c; tws[i] = s;
    }
    __syncthreads();
    for (int task = t; task < 512; task += 256) {
        int xx = task >> 3, ky = task & 7;
        float sr = 0.f, si = 0.f;
        const float* row = sh + xx * 66;
        const float* tc = twc + ky * 64;
        const float* ts = tws + ky * 64;
        for (int y = 0; y < 64; ++y) { sr += row[y] * tc[y]; si += row[y] * ts[y]; }
        s1[(xx * 8 + ky) * 2 + 0] = sr;
        s1[(xx * 8 + ky) * 2 + 1] = si;
    }
    __syncthreads();
    if (t < 128) {
        int kxi = t >> 3, ky = t & 7;
        int kx = (kxi < 8) ? kxi : (kxi - 16);   // negative freq alias of rows 56..63
        float ar = 0.f, ai = 0.f;
        for (int xx = 0; xx < 64; ++xx) {
            float s, c;
            sincosf(-2.f * PI_F * (float)(kx * xx) / 64.f, &s, &c);
            float vr = s1[(xx * 8 + ky) * 2], vi = s1[(xx * 8 + ky) * 2 + 1];
            ar += vr * c - vi * s;
            ai += vr * s + vi * c;
        }
        xf[((size_t)bc * 128 + t) * 2 + 0] = ar;
        xf[((size_t)bc * 128 + t) * 2 + 1] = ai;
    }
}

// ---------------- mode mix + truncated inverse x-DFT -> stt(b,o,64,8) complex ----------------
// Split from old k_mix_inv: this part keeps the per-(b,o) structure (cheap phases),
// writes the small stt spectral slab to global for k_pw.
__global__ __launch_bounds__(256) void k_mix(
    const float* __restrict__ xf,
    const float* __restrict__ w1, const float* __restrict__ w2,
    float* __restrict__ stt)
{
    int blk = blockIdx.x;
    int b = blk >> 5, o = blk & 31;
    int t = threadIdx.x;
    __shared__ float sxf[32 * 128 * 2];   // 32 KB
    __shared__ float sof[128 * 2];
    __shared__ float cxc[16 * 64], cxs[16 * 64];   // x-ifft twiddle table, 8 KB
    const float* xfb = xf + (size_t)b * 32 * 128 * 2;
    for (int i = t; i < 32 * 128 * 2; i += 256) sxf[i] = xfb[i];
    for (int i = t; i < 1024; i += 256) {
        int kxi = i >> 6, xx = i & 63;
        int kx = (kxi < 8) ? kxi : (kxi - 16);
        float s, c;
        sincosf(2.f * PI_F * (float)(kx * xx) / 64.f, &s, &c);
        cxc[i] = c; cxs[i] = s;
    }
    __syncthreads();
    if (t < 128) {                          // of[o] = sum_i xf[i] * w[i,o]
        int kxi = t >> 3, ky = t & 7;
        const float* w = (kxi < 8) ? w1 : w2;
        int kxw = kxi & 7;
        float ar = 0.f, ai = 0.f;
        for (int i = 0; i < 32; ++i) {
            size_t wi0 = (((size_t)(i * 32 + o) * 8 + kxw) * 8 + ky) * 2;
            float wr = w[wi0], wimag = w[wi0 + 1];
            float xr = sxf[(i * 128 + t) * 2], xi = sxf[(i * 128 + t) * 2 + 1];
            ar += xr * wr - xi * wimag;
            ai += xr * wimag + xi * wr;
        }
        sof[t * 2 + 0] = ar; sof[t * 2 + 1] = ai;
    }
    __syncthreads();
    for (int task = t; task < 512; task += 256) {   // ifft along x (1/64)
        int xx = task >> 3, ky = task & 7;
        float ar = 0.f, ai = 0.f;
        #pragma unroll
        for (int kxi = 0; kxi < 16; ++kxi) {
            float c = cxc[kxi * 64 + xx], s = cxs[kxi * 64 + xx];
            float vr = sof[(kxi * 8 + ky) * 2], vi = sof[(kxi * 8 + ky) * 2 + 1];
            ar += vr * c - vi * s;
            ai += vr * s + vi * c;
        }
        stt[(size_t)blk * 1024 + (xx * 8 + ky) * 2 + 0] = ar * (1.f / 64.f);
        stt[(size_t)blk * 1024 + (xx * 8 + ky) * 2 + 1] = ai * (1.f / 64.f);
    }
}

// ---------------- irfft-y + pointwise + gelu: block = (b, xx-row), all 32 out-channels ----------------
// h-tile loaded ONCE into LDS (kills the 32x h-reread of the old fused kernel);
// 256 blocks = full CU coverage on the heavy phase.
__global__ __launch_bounds__(256) void k_pw(
    const float* __restrict__ h, const float* __restrict__ stt,
    const float* __restrict__ wpt, const float* __restrict__ wptb,
    float* __restrict__ hout, int do_gelu)
{
    int blk = blockIdx.x;
    int b = blk >> 6, xx = blk & 63;
    int t = threadIdx.x;
    __shared__ float sh[32 * 64];       // h[c][y] tile, 8 KB
    __shared__ float sst[32 * 16];      // stt[o][ky]{r,i}, 2 KB
    __shared__ float swp[32 * 32];      // wpt[o][c], 4 KB
    __shared__ float swb[32];
    __shared__ float cy[8 * 64], sy[8 * 64];
    for (int i = t; i < 2048; i += 256) {
        int c = i >> 6, y = i & 63;
        sh[i] = h[((size_t)(b * 32 + c)) * 4096 + xx * 64 + y];
    }
    for (int i = t; i < 512; i += 256) {
        int o = i >> 4, r = i & 15;
        sst[i] = stt[((size_t)(b * 32 + o)) * 1024 + xx * 16 + r];
    }
    for (int i = t; i < 1024; i += 256) swp[i] = wpt[i];
    if (t < 32) swb[t] = wptb[t];
    for (int i = t; i < 512; i += 256) {
        int ky = i >> 6, y = i & 63;
        float s, c;
        sincosf(2.f * PI_F * (float)(ky * y) / 64.f, &s, &c);
        cy[i] = c; sy[i] = s;
    }
    __syncthreads();
    int o = t >> 3, y0 = t & 7;
    float wb = swb[o];
    #pragma unroll
    for (int k = 0; k < 8; ++k) {
        int y = y0 + 8 * k;
        // irfft along y, n=64: DC imag dropped (C2R semantics), Nyquist zero
        float sp = sst[o * 16 + 0];
        #pragma unroll
        for (int ky = 1; ky < 8; ++ky)
            sp += 2.f * (sst[o * 16 + ky * 2]     * cy[ky * 64 + y]
                       - sst[o * 16 + ky * 2 + 1] * sy[ky * 64 + y]);
        sp *= (1.f / 64.f);
        float pw = wb;
        #pragma unroll
        for (int c = 0; c < 32; ++c)
            pw += swp[o * 32 + c] * sh[c * 64 + y];
        float v = sp + pw;
        if (do_gelu) v = gelu_exact(v);
        hout[((size_t)(b * 32 + o)) * 4096 + xx * 64 + y] = v;
    }
}

// ---------------- centered 65x65 ortho-FFT modes: Fm(b,c,17,9) a=-8..8, b=-8..0 ----------------
__global__ __launch_bounds__(256) void k_nu_fm(const float* __restrict__ h, float* __restrict__ Fm)
{
    int bc = blockIdx.x;
    int t = threadIdx.x;
    __shared__ float sh[64 * 66];
    __shared__ float twc[9 * 64], tws[9 * 64];
    __shared__ float s1[64 * 9 * 2];
    const float* hp = h + (size_t)bc * 4096;
    for (int i = t; i < 4096; i += 256) sh[(i >> 6) * 66 + (i & 63)] = hp[i];
    for (int i = t; i < 9 * 64; i += 256) {
        int bbi = i >> 6, y = i & 63;
        float s, c;
        sincosf(-2.f * PI_F * (float)((bbi - 8) * y) / 65.f, &s, &c);
        twc[i] = c; tws[i] = s;
    }
    __syncthreads();
    for (int task = t; task < 64 * 9; task += 256) {
        int xx = task / 9, bbi = task % 9;
        float sr = 0.f, si = 0.f;
        const float* row = sh + xx * 66;
        const float* tc = twc + bbi * 64;
        const float* ts = tws + bbi * 64;
        for (int y = 0; y < 64; ++y) { sr += row[y] * tc[y]; si += row[y] * ts[y]; }
        s1[(xx * 9 + bbi) * 2 + 0] = sr;
        s1[(xx * 9 + bbi) * 2 + 1] = si;
    }
    __syncthreads();
    for (int task = t; task < 17 * 9; task += 256) {
        int ai2 = task / 9, bbi = task % 9;
        int afreq = ai2 - 8;
        float ar = 0.f, aim = 0.f;
        for (int xx = 0; xx < 64; ++xx) {
            float s, c;
            sincosf(-2.f * PI_F * (float)(afreq * xx) / 65.f, &s, &c);
            float vr = s1[(xx * 9 + bbi) * 2], vi = s1[(xx * 9 + bbi) * 2 + 1];
            ar += vr * c - vi * s;
            aim += vr * s + vi * c;
        }
        Fm[((size_t)bc * 153 + task) * 2 + 0] = ar * (1.f / 65.f);
        Fm[((size_t)bc * 153 + task) * 2 + 1] = aim * (1.f / 65.f);
    }
}

// ---------------- mode mix over channels + hermitian image assembly: images(b,s,17,17) ----------------
__global__ __launch_bounds__(256) void k_nu_img(
    const float* __restrict__ Fm, const float* __restrict__ nw1, const float* __restrict__ nw2,
    float* __restrict__ images)
{
    int blk = blockIdx.x;
    int b = blk >> 4, s = blk & 15;
    int t = threadIdx.x;
    __shared__ float im1[17 * 8 * 2];
    __shared__ float im2[9 * 2];
    if (t < 136) {
        int xx = t >> 3, y = t & 7;
        float ar = 0.f, ai = 0.f;
        for (int i = 0; i < 32; ++i) {
            size_t f0 = (((size_t)(b * 32 + i)) * 153 + xx * 9 + y) * 2;
            size_t w0 = (((size_t)(i * 16 + s) * 17 + xx) * 8 + y) * 2;
            float fr = Fm[f0], fi = Fm[f0 + 1];
            float wr = nw1[w0], wi = nw1[w0 + 1];
            ar += fr * wr - fi * wi;
            ai += fr * wi + fi * wr;
        }
        im1[t * 2] = ar; im1[t * 2 + 1] = ai;
    } else if (t < 145) {
        int k = t - 136;   // a = k-8, col b=0 (bbi=8)
        float ar = 0.f, ai = 0.f;
        for (int i = 0; i < 32; ++i) {
            size_t f0 = (((size_t)(b * 32 + i)) * 153 + k * 9 + 8) * 2;
            size_t w0 = ((size_t)(i * 16 + s) * 9 + k) * 2;
            float fr = Fm[f0], fi = Fm[f0 + 1];
            float wr = nw2[w0], wi = nw2[w0 + 1];
            ar += fr * wr - fi * wi;
            ai += fr * wi + fi * wr;
        }
        im2[k * 2] = ar; im2[k * 2 + 1] = ai;
    }
    __syncthreads();
    for (int task = t; task < 289; task += 256) {
        int xx = task / 17, y = task % 17;
        float vr, vi;
        if (y < 8)      { vr = im1[(xx * 8 + y) * 2];            vi = im1[(xx * 8 + y) * 2 + 1]; }
        else if (y > 8) { int sx = 16 - xx, sy2 = 16 - y;
                          vr = im1[(sx * 8 + sy2) * 2];          vi = -im1[(sx * 8 + sy2) * 2 + 1]; }
        else {
            if (xx < 8)       { vr = im2[xx * 2];        vi = im2[xx * 2 + 1]; }
            else if (xx == 8) { vr = im2[16];            vi = 0.f; }
            else              { vr = im2[(16 - xx) * 2]; vi = -im2[(16 - xx) * 2 + 1]; }
        }
        images[((size_t)blk * 289 + task) * 2 + 0] = vr;
        images[((size_t)blk * 289 + task) * 2 + 1] = vi;
    }
}

// ---------------- per-(b,s) bbox min/max over the subdomain's points ----------------
__global__ __launch_bounds__(256) void k_seg(
    const int* __restrict__ ind, const int* __restrict__ sep, const float* __restrict__ loc,
    float* __restrict__ mnmx)
{
    int blk = blockIdx.x;
    int b = blk >> 4, s = blk & 15;
    int t = threadIdx.x;
    int j0 = sep[b * 17 + s], j1 = sep[b * 17 + s + 1];
    float mn0 = 1e30f, mn1 = 1e30f, mx0 = -1e30f, mx1 = -1e30f;
    for (int j = j0 + t; j < j1; j += 256) {
        int p = ind[b * NYP + j];
        float l0 = loc[((size_t)b * NYP + p) * 2];
        float l1 = loc[((size_t)b * NYP + p) * 2 + 1];
        mn0 = fminf(mn0, l0); mx0 = fmaxf(mx0, l0);
        mn1 = fminf(mn1, l1); mx1 = fmaxf(mx1, l1);
    }
    __shared__ float r[4][256];
    r[0][t] = mn0; r[1][t] = mn1; r[2][t] = mx0; r[3][t] = mx1;
    __syncthreads();
    for (int st = 128; st > 0; st >>= 1) {
        if (t < st) {
            r[0][t] = fminf(r[0][t], r[0][t + st]);
            r[1][t] = fminf(r[1][t], r[1][t + st]);
            r[2][t] = fmaxf(r[2][t], r[2][t + st]);
            r[3][t] = fmaxf(r[3][t], r[3][t + st]);
        }
        __syncthreads();
    }
    if (t == 0) {
        mnmx[blk * 4 + 0] = r[0][0]; mnmx[blk * 4 + 1] = r[1][0];
        mnmx[blk * 4 + 2] = r[2][0]; mnmx[blk * 4 + 3] = r[3][0];
    }
}

// ---------------- exact type-2 NUDFT per point, only its own subdomain ----------------
__global__ __launch_bounds__(256) void k_nudft(
    const int* __restrict__ ind, const int* __restrict__ sep, const float* __restrict__ loc,
    const float* __restrict__ images, const float* __restrict__ mnmx,
    const float* __restrict__ nu_w, const float* __restrict__ nu_b,
    float* __restrict__ xnu)
{
    int blk = blockIdx.x;
    int b = blk >> 4, s = blk & 15;
    int t = threadIdx.x;
    __shared__ float img[289 * 2];
    for (int i = t; i < 578; i += 256) img[i] = images[(size_t)blk * 578 + i];
    __syncthreads();
    int j0 = sep[b * 17 + s], j1 = sep[b * 17 + s + 1];
    float mn0 = mnmx[blk * 4], mn1 = mnmx[blk * 4 + 1];
    float mx0 = mnmx[blk * 4 + 2], mx1 = mnmx[blk * 4 + 3];
    float nuw = nu_w[s], nub = nu_b[s];
    const float TWO_PI = 6.28318530717958647692f;
    for (int j = j0 + t; j < j1; j += 256) {
        int p = ind[b * NYP + j];
        float l0 = loc[((size_t)b * NYP + p) * 2];
        float l1 = loc[((size_t)b * NYP + p) * 2 + 1];
        float om0 = (l0 - mn0) / (mx0 - mn0 + 1e-6f) * TWO_PI - PI_F;
        float om1 = (l1 - mn1) / (mx1 - mn1 + 1e-6f) * TWO_PI - PI_F;
        float stepxs, stepxc, stepys, stepyc;
        sincosf(om0, &stepxs, &stepxc);
        sincosf(om1, &stepys, &stepyc);
        float ex_i, ex_r, ey0_i, ey0_r;
        sincosf(-8.f * om0, &ex_i, &ex_r);
        sincosf(-8.f * om1, &ey0_i, &ey0_r);
        float tot = 0.f;
        for (int xx = 0; xx < 17; ++xx) {
            float inr = 0.f, ini = 0.f;
            float eyr = ey0_r, eyi = ey0_i;
            const float* row = img + xx * 34;
            #pragma unroll
            for (int y = 0; y < 17; ++y) {
                float ir = row[y * 2], ii = row[y * 2 + 1];
                inr += ir * eyr - ii * eyi;
                ini += ir * eyi + ii * eyr;
                float nr = eyr * stepyc - eyi * stepys;
                eyi = eyr * stepys + eyi * stepyc;
                eyr = nr;
            }
            tot += ex_r * inr - ex_i * ini;
            float nr = ex_r * stepxc - ex_i * stepxs;
            ex_i = ex_r * stepxs + ex_i * stepxc;
            ex_r = nr;
        }
        xnu[(size_t)b * NYP + p] = (tot * (1.f / 17.f)) * nuw + nub;
    }
}

// ---------------- head MLP: q(b,g) = fc2(gelu(fc1(h[b,:,g]))) ----------------
__global__ __launch_bounds__(256) void k_head(
    const float* __restrict__ h, const float* __restrict__ Wfc1, const float* __restrict__ bfc1,
    const float* __restrict__ Wfc2, const float* __restrict__ bfc2, float* __restrict__ q)
{
    __shared__ float w1s[128 * 32];
    __shared__ float b1s[128];
    __shared__ float w2s[128];
    int t = threadIdx.x;
    for (int i = t; i < 4096; i += 256) w1s[i] = Wfc1[i];
    if (t < 128) { b1s[t] = bfc1[t]; w2s[t] = Wfc2[t]; }
    __syncthreads();
    int id = blockIdx.x * 256 + t;
    int b = id >> 12, g = id & 4095;
    float hv[32];
    #pragma unroll
    for (int c = 0; c < 32; ++c) hv[c] = h[((size_t)(b * 32 + c)) * GG + g];
    float acc = bfc2[0];
    for (int j = 0; j < 128; ++j) {
        float z = b1s[j];
        #pragma unroll
        for (int c = 0; c < 32; ++c) z += w1s[j * 32 + c] * hv[c];
        acc += w2s[j] * gelu_exact(z);
    }
    q[id] = acc;
}

// ---------------- de3 decoder + final combine with x_nu ----------------
__global__ __launch_bounds__(256) void k_de3(
    const float* __restrict__ Wde3, const float* __restrict__ bde3,
    const float* __restrict__ q, const float* __restrict__ xnu, float* __restrict__ out)
{
    int nbase = blockIdx.x * 8;
    int t = threadIdx.x;
    float acc[32];
    #pragma unroll
    for (int k = 0; k < 32; ++k) acc[k] = 0.f;
    for (int g4 = t; g4 < GG / 4; g4 += 256) {
        float4 qb[4];
        #pragma unroll
        for (int b = 0; b < 4; ++b)
            qb[b] = ((const float4*)(q + (size_t)b * GG))[g4];
        float4 w[8];
        #pragma unroll
        for (int r = 0; r < 8; ++r)
            w[r] = ((const float4*)(Wde3 + (size_t)(nbase + r) * GG))[g4];
        #pragma unroll
        for (int r = 0; r < 8; ++r)
            #pragma unroll
            for (int b = 0; b < 4; ++b)
                acc[r * 4 + b] += w[r].x * qb[b].x + w[r].y * qb[b].y
                                + w[r].z * qb[b].z + w[r].w * qb[b].w;
    }
    #pragma unroll
    for (int k = 0; k < 32; ++k)
        for (int off = 32; off > 0; off >>= 1) acc[k] += __shfl_down(acc[k], off);
    __shared__ float red[4][32];
    int wave = t >> 6, lane = t & 63;
    if (lane == 0)
        for (int k = 0; k < 32; ++k) red[wave][k] = acc[k];
    __syncthreads();
    if (t < 32) {
        float v = red[0][t] + red[1][t] + red[2][t] + red[3][t];
        int r = t >> 2, b = t & 3;
        int n = nbase + r;
        out[(size_t)b * NYP + n] = v + bde3[n] + xnu[(size_t)b * NYP + n];
    }
}

extern "C" void kernel_launch(void* const* d_in, const int* in_sizes, int n_in,
                              void* d_out, int out_size, void* d_ws, size_t ws_size,
                              hipStream_t stream) {
    const float* x    = (const float*)d_in[0];
    const float* loc  = (const float*)d_in[1];
    const int*   ind  = (const int*)d_in[2];
    const int*   sep  = (const int*)d_in[3];
    const float* We1  = (const float*)d_in[4];
    const float* be1  = (const float*)d_in[5];
    const float* We2  = (const float*)d_in[6];
    const float* be2  = (const float*)d_in[7];
    const float* Wfc0 = (const float*)d_in[8];
    const float* bfc0 = (const float*)d_in[9];
    const float* cw1  = (const float*)d_in[10];
    const float* cw2  = (const float*)d_in[11];
    const float* wpt  = (const float*)d_in[12];
    const float* wptb = (const float*)d_in[13];
    const float* nw1  = (const float*)d_in[14];
    const float* nw2  = (const float*)d_in[15];
    const float* nuw  = (const float*)d_in[16];
    const float* nub  = (const float*)d_in[17];
    const float* Wde3 = (const float*)d_in[18];
    const float* bde3 = (const float*)d_in[19];
    const float* Wfc1 = (const float*)d_in[20];
    const float* bfc1 = (const float*)d_in[21];
    const float* Wfc2 = (const float*)d_in[22];
    const float* bfc2 = (const float*)d_in[23];
    float* out = (float*)d_out;

    float* ws     = (float*)d_ws;
    float* hA     = ws;                                   // B*32*G = 524288
    float* hB     = hA + (size_t)BB * WIDTH * GG;         // 524288
    float* xfbuf  = hB + (size_t)BB * WIDTH * GG;         // B*32*128*2 = 65536
    float* Fm     = xfbuf + (size_t)BB * WIDTH * 128 * 2; // B*32*153*2 = 39168
    float* images = Fm + (size_t)BB * WIDTH * 153 * 2;    // B*S*289*2 = 36992
    float* mnmx   = images + (size_t)BB * SS * 289 * 2;   // 256
    float* q      = mnmx + 256;                           // B*G = 16384
    float* xnu    = q + (size_t)BB * GG;                  // B*NY = 32768
    float* sttbuf = xnu + (size_t)BB * NYP;               // B*32*64*8*2 = 131072

    k_seg<<<BB * SS, 256, 0, stream>>>(ind, sep, loc, mnmx);
    k_embed<<<GG / 8, 256, 0, stream>>>(x, loc, We1, be1, We2, be2, Wfc0, bfc0, hA);

    const float* hin = hA;
    float* hout = hB;
    for (int l = 0; l < 4; ++l) {
        k_xf<<<BB * WIDTH, 256, 0, stream>>>(hin, xfbuf);
        k_mix<<<BB * WIDTH, 256, 0, stream>>>(xfbuf,
                                              cw1 + (size_t)l * 16384, cw2 + (size_t)l * 16384,
                                              sttbuf);
        k_pw<<<BB * 64, 256, 0, stream>>>(hin, sttbuf, wpt + l * 1024, wptb + l * 32,
                                          hout, (l < 3) ? 1 : 0);
        float* tmp = (float*)hin; hin = hout; hout = tmp;
    }
    // hin now = hA = final trunk activation
    k_nu_fm<<<BB * WIDTH, 256, 0, stream>>>(hin, Fm);
    k_nu_img<<<BB * SS, 256, 0, stream>>>(Fm, nw1, nw2, images);
    k_nudft<<<BB * SS, 256, 0, stream>>>(ind, sep, loc, images, mnmx, nuw, nub, xnu);
    k_head<<<(BB * GG) / 256, 256, 0, stream>>>(hin, Wfc1, bfc1, Wfc2, bfc2, q);
    k_de3<<<NYP / 8, 256, 0, stream>>>(Wde3, bde3, q, xnu, out);
}

// Round 5
// 571.566 us; speedup vs baseline: 1.3989x; 1.0504x over previous
//
#include <hip/hip_runtime.h>
#include <math.h>

#define BB 4
#define NX 4096
#define NYP 8192
#define GG 4096
#define WIDTH 32
#define SS 16
#define PI_F 3.14159265358979323846f

__device__ __forceinline__ float gelu_exact(float v) {
    return 0.5f * v * (1.0f + erff(v * 0.70710678118654752f));
}

// ---------------- embed (2 matvec families) + fc0 -> h0 (B,32,64,64) ----------------
// PARKED: r=2/4/8 all ~89us, FETCH invariant ~100MB @1.17TB/s -> not partition-limited.
__global__ __launch_bounds__(256, 2) void k_embed(
    const float* __restrict__ x, const float* __restrict__ loc,
    const float* __restrict__ We1, const float* __restrict__ be1,
    const float* __restrict__ We2, const float* __restrict__ be2,
    const float* __restrict__ Wfc0, const float* __restrict__ bfc0,
    float* __restrict__ h0)
{
    int gbase = blockIdx.x * 8;
    int t = threadIdx.x;

    float accx[32];
    #pragma unroll
    for (int k = 0; k < 32; ++k) accx[k] = 0.f;
    for (int n4 = t; n4 < NX / 4; n4 += 256) {
        float4 xb[4];
        #pragma unroll
        for (int b = 0; b < 4; ++b)
            xb[b] = ((const float4*)(x + (size_t)b * NX))[n4];
        float4 w[8];
        #pragma unroll
        for (int r = 0; r < 8; ++r)
            w[r] = ((const float4*)(We1 + (size_t)(gbase + r) * NX))[n4];
        #pragma unroll
        for (int r = 0; r < 8; ++r)
            #pragma unroll
            for (int b = 0; b < 4; ++b)
                accx[r * 4 + b] += w[r].x * xb[b].x + w[r].y * xb[b].y
                                 + w[r].z * xb[b].z + w[r].w * xb[b].w;
    }

    float accl[64];
    #pragma unroll
    for (int k = 0; k < 64; ++k) accl[k] = 0.f;
    for (int n4 = t; n4 < NYP / 4; n4 += 256) {
        float4 p0[4], p1[4];
        #pragma unroll
        for (int b = 0; b < 4; ++b) {
            const float4* lb = (const float4*)(loc + (size_t)b * NYP * 2);
            p0[b] = lb[n4 * 2];
            p1[b] = lb[n4 * 2 + 1];
        }
        float4 w[8];
        #pragma unroll
        for (int r = 0; r < 8; ++r)
            w[r] = ((const float4*)(We2 + (size_t)(gbase + r) * NYP))[n4];
        #pragma unroll
        for (int r = 0; r < 8; ++r)
            #pragma unroll
            for (int b = 0; b < 4; ++b) {
                accl[r * 4 + b]      += w[r].x * p0[b].x + w[r].y * p0[b].z
                                      + w[r].z * p1[b].x + w[r].w * p1[b].z;
                accl[32 + r * 4 + b] += w[r].x * p0[b].y + w[r].y * p0[b].w
                                      + w[r].z * p1[b].y + w[r].w * p1[b].w;
            }
    }

    #pragma unroll
    for (int k = 0; k < 32; ++k)
        for (int off = 32; off > 0; off >>= 1) accx[k] += __shfl_down(accx[k], off);
    #pragma unroll
    for (int k = 0; k < 64; ++k)
        for (int off = 32; off > 0; off >>= 1) accl[k] += __shfl_down(accl[k], off);
    __shared__ float red[4][96];
    __shared__ float tot[96];
    int wave = t >> 6, lane = t & 63;
    if (lane == 0) {
        for (int k = 0; k < 32; ++k) red[wave][k] = accx[k];
        for (int k = 0; k < 64; ++k) red[wave][32 + k] = accl[k];
    }
    __syncthreads();
    if (t < 96) tot[t] = red[0][t] + red[1][t] + red[2][t] + red[3][t];
    __syncthreads();
    if (t < 128) {
        int b = t >> 5, w = t & 31;
        float w0 = Wfc0[w * 3 + 0], w1c = Wfc0[w * 3 + 1], w2c = Wfc0[w * 3 + 2], bb0 = bfc0[w];
        #pragma unroll
        for (int r = 0; r < 8; ++r) {
            int g = gbase + r;
            float xe = tot[r * 4 + b] + be1[g];
            float l0 = tot[32 + r * 4 + b] + be2[g];
            float l1 = tot[64 + r * 4 + b] + be2[g];
            h0[((size_t)(b * WIDTH + w)) * GG + g] = xe * w0 + l0 * w1c + l1 * w2c + bb0;
        }
    }
}

// ---------------- truncated forward DFT: h(b,c,64,64) -> xf(b,c,16,8) complex ----------------
__global__ __launch_bounds__(256) void k_xf(const float* __restrict__ h, float* __restrict__ xf)
{
    int bc = blockIdx.x;
    int t = threadIdx.x;
    __shared__ float sh[64 * 66];          // padded rows: bank-conflict-free stage-1
    __shared__ float twc[8 * 64], tws[8 * 64];
    __shared__ float tb64c[64], tb64s[64]; // e^{-2*pi*i*m/64}
    __shared__ float s1[64 * 8 * 2];
    const float* hp = h + (size_t)bc * 4096;
    for (int i = t; i < 4096; i += 256) sh[(i >> 6) * 66 + (i & 63)] = hp[i];
    for (int i = t; i < 512; i += 256) {
        int ky = i >> 6, y = i & 63;
        float s, c;
        sincosf(-2.f * PI_F * (float)(ky * y) / 64.f, &s, &c);
        twc[i] = c; tws[i] = s;
    }
    if (t < 64) {
        float s, c;
        sincosf(-2.f * PI_F * (float)t / 64.f, &s, &c);
        tb64c[t] = c; tb64s[t] = s;
    }
    __syncthreads();
    for (int task = t; task < 512; task += 256) {
        int xx = task >> 3, ky = task & 7;
        float sr = 0.f, si = 0.f;
        const float* row = sh + xx * 66;
        const float* tc = twc + ky * 64;
        const float* ts = tws + ky * 64;
        for (int y = 0; y < 64; ++y) { sr += row[y] * tc[y]; si += row[y] * ts[y]; }
        s1[(xx * 8 + ky) * 2 + 0] = sr;
        s1[(xx * 8 + ky) * 2 + 1] = si;
    }
    __syncthreads();
    if (t < 128) {
        int kxi = t >> 3, ky = t & 7;
        int kx = (kxi < 8) ? kxi : (kxi - 16);   // negative freq alias of rows 56..63
        float ar = 0.f, ai = 0.f;
        int m = 0;                               // (kx*xx) mod 64, incremental
        for (int xx = 0; xx < 64; ++xx) {
            float c = tb64c[m], s = tb64s[m];
            float vr = s1[(xx * 8 + ky) * 2], vi = s1[(xx * 8 + ky) * 2 + 1];
            ar += vr * c - vi * s;
            ai += vr * s + vi * c;
            m = (m + kx) & 63;
        }
        xf[((size_t)bc * 128 + t) * 2 + 0] = ar;
        xf[((size_t)bc * 128 + t) * 2 + 1] = ai;
    }
}

// ---------------- mode mix + truncated inverse x-DFT -> stt(b,o,64,8) complex ----------------
__global__ __launch_bounds__(256) void k_mix(
    const float* __restrict__ xf,
    const float* __restrict__ w1, const float* __restrict__ w2,
    float* __restrict__ stt)
{
    int blk = blockIdx.x;
    int b = blk >> 5, o = blk & 31;
    int t = threadIdx.x;
    __shared__ float sxf[32 * 128 * 2];   // 32 KB
    __shared__ float sof[128 * 2];
    __shared__ float cxc[16 * 64], cxs[16 * 64];   // x-ifft twiddle table, 8 KB
    __shared__ float sw1[32 * 128], sw2[32 * 128]; // per-o weight slices, 32 KB
    const float* xfb = xf + (size_t)b * 32 * 128 * 2;
    for (int i = t; i < 32 * 128 * 2; i += 256) sxf[i] = xfb[i];
    for (int i = t; i < 32 * 128; i += 256) {      // coalesced 128-float rows
        int ii = i >> 7, e = i & 127;
        sw1[i] = w1[((size_t)(ii * 32 + o)) * 128 + e];
        sw2[i] = w2[((size_t)(ii * 32 + o)) * 128 + e];
    }
    for (int i = t; i < 1024; i += 256) {
        int kxi = i >> 6, xx = i & 63;
        int kx = (kxi < 8) ? kxi : (kxi - 16);
        float s, c;
        sincosf(2.f * PI_F * (float)(kx * xx) / 64.f, &s, &c);
        cxc[i] = c; cxs[i] = s;
    }
    __syncthreads();
    if (t < 128) {                          // of[o] = sum_i xf[i] * w[i,o]
        int kxi = t >> 3, ky = t & 7;
        const float* w = (kxi < 8) ? sw1 : sw2;
        int kxw = kxi & 7;
        int e = (kxw * 8 + ky) * 2;
        float ar = 0.f, ai = 0.f;
        #pragma unroll
        for (int i = 0; i < 32; ++i) {
            float wr = w[i * 128 + e], wimag = w[i * 128 + e + 1];
            float xr = sxf[(i * 128 + t) * 2], xi = sxf[(i * 128 + t) * 2 + 1];
            ar += xr * wr - xi * wimag;
            ai += xr * wimag + xi * wr;
        }
        sof[t * 2 + 0] = ar; sof[t * 2 + 1] = ai;
    }
    __syncthreads();
    for (int task = t; task < 512; task += 256) {   // ifft along x (1/64)
        int xx = task >> 3, ky = task & 7;
        float ar = 0.f, ai = 0.f;
        #pragma unroll
        for (int kxi = 0; kxi < 16; ++kxi) {
            float c = cxc[kxi * 64 + xx], s = cxs[kxi * 64 + xx];
            float vr = sof[(kxi * 8 + ky) * 2], vi = sof[(kxi * 8 + ky) * 2 + 1];
            ar += vr * c - vi * s;
            ai += vr * s + vi * c;
        }
        stt[(size_t)blk * 1024 + (xx * 8 + ky) * 2 + 0] = ar * (1.f / 64.f);
        stt[(size_t)blk * 1024 + (xx * 8 + ky) * 2 + 1] = ai * (1.f / 64.f);
    }
}

// ---------------- irfft-y + pointwise + gelu: block = (b, xx-row), all 32 out-channels ----------------
__global__ __launch_bounds__(256) void k_pw(
    const float* __restrict__ h, const float* __restrict__ stt,
    const float* __restrict__ wpt, const float* __restrict__ wptb,
    float* __restrict__ hout, int do_gelu)
{
    int blk = blockIdx.x;
    int b = blk >> 6, xx = blk & 63;
    int t = threadIdx.x;
    __shared__ float sh[32 * 64];       // h[c][y] tile, 8 KB
    __shared__ float sst[32 * 16];      // stt[o][ky]{r,i}, 2 KB
    __shared__ float swp[32 * 32];      // wpt[o][c], 4 KB
    __shared__ float swb[32];
    __shared__ float cy[8 * 64], sy[8 * 64];
    for (int i = t; i < 2048; i += 256) {
        int c = i >> 6, y = i & 63;
        sh[i] = h[((size_t)(b * 32 + c)) * 4096 + xx * 64 + y];
    }
    for (int i = t; i < 512; i += 256) {
        int o = i >> 4, r = i & 15;
        sst[i] = stt[((size_t)(b * 32 + o)) * 1024 + xx * 16 + r];
    }
    for (int i = t; i < 1024; i += 256) swp[i] = wpt[i];
    if (t < 32) swb[t] = wptb[t];
    for (int i = t; i < 512; i += 256) {
        int ky = i >> 6, y = i & 63;
        float s, c;
        sincosf(2.f * PI_F * (float)(ky * y) / 64.f, &s, &c);
        cy[i] = c; sy[i] = s;
    }
    __syncthreads();
    int o = t >> 3, y0 = t & 7;
    float wb = swb[o];
    #pragma unroll
    for (int k = 0; k < 8; ++k) {
        int y = y0 + 8 * k;
        // irfft along y, n=64: DC imag dropped (C2R semantics), Nyquist zero
        float sp = sst[o * 16 + 0];
        #pragma unroll
        for (int ky = 1; ky < 8; ++ky)
            sp += 2.f * (sst[o * 16 + ky * 2]     * cy[ky * 64 + y]
                       - sst[o * 16 + ky * 2 + 1] * sy[ky * 64 + y]);
        sp *= (1.f / 64.f);
        float pw = wb;
        #pragma unroll
        for (int c = 0; c < 32; ++c)
            pw += swp[o * 32 + c] * sh[c * 64 + y];
        float v = sp + pw;
        if (do_gelu) v = gelu_exact(v);
        hout[((size_t)(b * 32 + o)) * 4096 + xx * 64 + y] = v;
    }
}

// ---------------- centered 65x65 ortho-FFT modes: Fm(b,c,17,9) a=-8..8, b=-8..0 ----------------
__global__ __launch_bounds__(256) void k_nu_fm(const float* __restrict__ h, float* __restrict__ Fm)
{
    int bc = blockIdx.x;
    int t = threadIdx.x;
    __shared__ float sh[64 * 66];
    __shared__ float twc[9 * 64], tws[9 * 64];
    __shared__ float t65c[65], t65s[65];   // e^{-2*pi*i*m/65}
    __shared__ float s1[64 * 9 * 2];
    const float* hp = h + (size_t)bc * 4096;
    for (int i = t; i < 4096; i += 256) sh[(i >> 6) * 66 + (i & 63)] = hp[i];
    for (int i = t; i < 9 * 64; i += 256) {
        int bbi = i >> 6, y = i & 63;
        float s, c;
        sincosf(-2.f * PI_F * (float)((bbi - 8) * y) / 65.f, &s, &c);
        twc[i] = c; tws[i] = s;
    }
    if (t < 65) {
        float s, c;
        sincosf(-2.f * PI_F * (float)t / 65.f, &s, &c);
        t65c[t] = c; t65s[t] = s;
    }
    __syncthreads();
    for (int task = t; task < 64 * 9; task += 256) {
        int xx = task / 9, bbi = task % 9;
        float sr = 0.f, si = 0.f;
        const float* row = sh + xx * 66;
        const float* tc = twc + bbi * 64;
        const float* ts = tws + bbi * 64;
        for (int y = 0; y < 64; ++y) { sr += row[y] * tc[y]; si += row[y] * ts[y]; }
        s1[(xx * 9 + bbi) * 2 + 0] = sr;
        s1[(xx * 9 + bbi) * 2 + 1] = si;
    }
    __syncthreads();
    for (int task = t; task < 17 * 9; task += 256) {
        int ai2 = task / 9, bbi = task % 9;
        int afreq = ai2 - 8;
        float ar = 0.f, aim = 0.f;
        int m = 0;                             // (afreq*xx) mod 65, incremental
        for (int xx = 0; xx < 64; ++xx) {
            float c = t65c[m], s = t65s[m];
            float vr = s1[(xx * 9 + bbi) * 2], vi = s1[(xx * 9 + bbi) * 2 + 1];
            ar += vr * c - vi * s;
            aim += vr * s + vi * c;
            m += afreq;
            if (m < 0) m += 65;
            else if (m >= 65) m -= 65;
        }
        Fm[((size_t)bc * 153 + task) * 2 + 0] = ar * (1.f / 65.f);
        Fm[((size_t)bc * 153 + task) * 2 + 1] = aim * (1.f / 65.f);
    }
}

// ---------------- mode mix over channels + hermitian image assembly: images(b,s,17,17) ----------------
__global__ __launch_bounds__(256) void k_nu_img(
    const float* __restrict__ Fm, const float* __restrict__ nw1, const float* __restrict__ nw2,
    float* __restrict__ images)
{
    int blk = blockIdx.x;
    int b = blk >> 4, s = blk & 15;
    int t = threadIdx.x;
    __shared__ float im1[17 * 8 * 2];
    __shared__ float im2[9 * 2];
    if (t < 136) {
        int xx = t >> 3, y = t & 7;
        float ar = 0.f, ai = 0.f;
        for (int i = 0; i < 32; ++i) {
            size_t f0 = (((size_t)(b * 32 + i)) * 153 + xx * 9 + y) * 2;
            size_t w0 = (((size_t)(i * 16 + s) * 17 + xx) * 8 + y) * 2;
            float fr = Fm[f0], fi = Fm[f0 + 1];
            float wr = nw1[w0], wi = nw1[w0 + 1];
            ar += fr * wr - fi * wi;
            ai += fr * wi + fi * wr;
        }
        im1[t * 2] = ar; im1[t * 2 + 1] = ai;
    } else if (t < 145) {
        int k = t - 136;   // a = k-8, col b=0 (bbi=8)
        float ar = 0.f, ai = 0.f;
        for (int i = 0; i < 32; ++i) {
            size_t f0 = (((size_t)(b * 32 + i)) * 153 + k * 9 + 8) * 2;
            size_t w0 = ((size_t)(i * 16 + s) * 9 + k) * 2;
            float fr = Fm[f0], fi = Fm[f0 + 1];
            float wr = nw2[w0], wi = nw2[w0 + 1];
            ar += fr * wr - fi * wi;
            ai += fr * wi + fi * wr;
        }
        im2[k * 2] = ar; im2[k * 2 + 1] = ai;
    }
    __syncthreads();
    for (int task = t; task < 289; task += 256) {
        int xx = task / 17, y = task % 17;
        float vr, vi;
        if (y < 8)      { vr = im1[(xx * 8 + y) * 2];            vi = im1[(xx * 8 + y) * 2 + 1]; }
        else if (y > 8) { int sx = 16 - xx, sy2 = 16 - y;
                          vr = im1[(sx * 8 + sy2) * 2];          vi = -im1[(sx * 8 + sy2) * 2 + 1]; }
        else {
            if (xx < 8)       { vr = im2[xx * 2];        vi = im2[xx * 2 + 1]; }
            else if (xx == 8) { vr = im2[16];            vi = 0.f; }
            else              { vr = im2[(16 - xx) * 2]; vi = -im2[(16 - xx) * 2 + 1]; }
        }
        images[((size_t)blk * 289 + task) * 2 + 0] = vr;
        images[((size_t)blk * 289 + task) * 2 + 1] = vi;
    }
}

// ---------------- exact type-2 NUDFT per point (bbox fused in-block) ----------------
__global__ __launch_bounds__(256) void k_nudft(
    const int* __restrict__ ind, const int* __restrict__ sep, const float* __restrict__ loc,
    const float* __restrict__ images,
    const float* __restrict__ nu_w, const float* __restrict__ nu_b,
    float* __restrict__ xnu)
{
    int blk = blockIdx.x;
    int b = blk >> 4, s = blk & 15;
    int t = threadIdx.x;
    __shared__ float img[289 * 2];
    __shared__ float r[4][256];
    for (int i = t; i < 578; i += 256) img[i] = images[(size_t)blk * 578 + i];
    int j0 = sep[b * 17 + s], j1 = sep[b * 17 + s + 1];
    // in-block bbox over the subdomain's points (was k_seg)
    float mn0 = 1e30f, mn1 = 1e30f, mx0 = -1e30f, mx1 = -1e30f;
    for (int j = j0 + t; j < j1; j += 256) {
        int p = ind[b * NYP + j];
        float l0 = loc[((size_t)b * NYP + p) * 2];
        float l1 = loc[((size_t)b * NYP + p) * 2 + 1];
        mn0 = fminf(mn0, l0); mx0 = fmaxf(mx0, l0);
        mn1 = fminf(mn1, l1); mx1 = fmaxf(mx1, l1);
    }
    r[0][t] = mn0; r[1][t] = mn1; r[2][t] = mx0; r[3][t] = mx1;
    __syncthreads();
    for (int st = 128; st > 0; st >>= 1) {
        if (t < st) {
            r[0][t] = fminf(r[0][t], r[0][t + st]);
            r[1][t] = fminf(r[1][t], r[1][t + st]);
            r[2][t] = fmaxf(r[2][t], r[2][t + st]);
            r[3][t] = fmaxf(r[3][t], r[3][t + st]);
        }
        __syncthreads();
    }
    mn0 = r[0][0]; mn1 = r[1][0]; mx0 = r[2][0]; mx1 = r[3][0];
    float nuw = nu_w[s], nub = nu_b[s];
    const float TWO_PI = 6.28318530717958647692f;
    for (int j = j0 + t; j < j1; j += 256) {
        int p = ind[b * NYP + j];
        float l0 = loc[((size_t)b * NYP + p) * 2];
        float l1 = loc[((size_t)b * NYP + p) * 2 + 1];
        float om0 = (l0 - mn0) / (mx0 - mn0 + 1e-6f) * TWO_PI - PI_F;
        float om1 = (l1 - mn1) / (mx1 - mn1 + 1e-6f) * TWO_PI - PI_F;
        float stepxs, stepxc, stepys, stepyc;
        sincosf(om0, &stepxs, &stepxc);
        sincosf(om1, &stepys, &stepyc);
        float ex_i, ex_r, ey0_i, ey0_r;
        sincosf(-8.f * om0, &ex_i, &ex_r);
        sincosf(-8.f * om1, &ey0_i, &ey0_r);
        float tot = 0.f;
        for (int xx = 0; xx < 17; ++xx) {
            float inr = 0.f, ini = 0.f;
            float eyr = ey0_r, eyi = ey0_i;
            const float* row = img + xx * 34;
            #pragma unroll
            for (int y = 0; y < 17; ++y) {
                float ir = row[y * 2], ii = row[y * 2 + 1];
                inr += ir * eyr - ii * eyi;
                ini += ir * eyi + ii * eyr;
                float nr = eyr * stepyc - eyi * stepys;
                eyi = eyr * stepys + eyi * stepyc;
                eyr = nr;
            }
            tot += ex_r * inr - ex_i * ini;
            float nr = ex_r * stepxc - ex_i * stepxs;
            ex_i = ex_r * stepxs + ex_i * stepxc;
            ex_r = nr;
        }
        xnu[(size_t)b * NYP + p] = (tot * (1.f / 17.f)) * nuw + nub;
    }
}

// ---------------- head MLP: q(b,g) = fc2(gelu(fc1(h[b,:,g]))) ----------------
__global__ __launch_bounds__(256) void k_head(
    const float* __restrict__ h, const float* __restrict__ Wfc1, const float* __restrict__ bfc1,
    const float* __restrict__ Wfc2, const float* __restrict__ bfc2, float* __restrict__ q)
{
    __shared__ float w1s[128 * 32];
    __shared__ float b1s[128];
    __shared__ float w2s[128];
    int t = threadIdx.x;
    for (int i = t; i < 4096; i += 256) w1s[i] = Wfc1[i];
    if (t < 128) { b1s[t] = bfc1[t]; w2s[t] = Wfc2[t]; }
    __syncthreads();
    int id = blockIdx.x * 256 + t;
    int b = id >> 12, g = id & 4095;
    float hv[32];
    #pragma unroll
    for (int c = 0; c < 32; ++c) hv[c] = h[((size_t)(b * 32 + c)) * GG + g];
    float acc = bfc2[0];
    for (int j = 0; j < 128; ++j) {
        float z = b1s[j];
        #pragma unroll
        for (int c = 0; c < 32; ++c) z += w1s[j * 32 + c] * hv[c];
        acc += w2s[j] * gelu_exact(z);
    }
    q[id] = acc;
}

// ---------------- de3 decoder + final combine with x_nu ----------------
__global__ __launch_bounds__(256) void k_de3(
    const float* __restrict__ Wde3, const float* __restrict__ bde3,
    const float* __restrict__ q, const float* __restrict__ xnu, float* __restrict__ out)
{
    int nbase = blockIdx.x * 8;
    int t = threadIdx.x;
    float acc[32];
    #pragma unroll
    for (int k = 0; k < 32; ++k) acc[k] = 0.f;
    for (int g4 = t; g4 < GG / 4; g4 += 256) {
        float4 qb[4];
        #pragma unroll
        for (int b = 0; b < 4; ++b)
            qb[b] = ((const float4*)(q + (size_t)b * GG))[g4];
        float4 w[8];
        #pragma unroll
        for (int r = 0; r < 8; ++r)
            w[r] = ((const float4*)(Wde3 + (size_t)(nbase + r) * GG))[g4];
        #pragma unroll
        for (int r = 0; r < 8; ++r)
            #pragma unroll
            for (int b = 0; b < 4; ++b)
                acc[r * 4 + b] += w[r].x * qb[b].x + w[r].y * qb[b].y
                                + w[r].z * qb[b].z + w[r].w * qb[b].w;
    }
    #pragma unroll
    for (int k = 0; k < 32; ++k)
        for (int off = 32; off > 0; off >>= 1) acc[k] += __shfl_down(acc[k], off);
    __shared__ float red[4][32];
    int wave = t >> 6, lane = t & 63;
    if (lane == 0)
        for (int k = 0; k < 32; ++k) red[wave][k] = acc[k];
    __syncthreads();
    if (t < 32) {
        float v = red[0][t] + red[1][t] + red[2][t] + red[3][t];
        int r = t >> 2, b = t & 3;
        int n = nbase + r;
        out[(size_t)b * NYP + n] = v + bde3[n] + xnu[(size_t)b * NYP + n];
    }
}

extern "C" void kernel_launch(void* const* d_in, const int* in_sizes, int n_in,
                              void* d_out, int out_size, void* d_ws, size_t ws_size,
                              hipStream_t stream) {
    const float* x    = (const float*)d_in[0];
    const float* loc  = (const float*)d_in[1];
    const int*   ind  = (const int*)d_in[2];
    const int*   sep  = (const int*)d_in[3];
    const float* We1  = (const float*)d_in[4];
    const float* be1  = (const float*)d_in[5];
    const float* We2  = (const float*)d_in[6];
    const float* be2  = (const float*)d_in[7];
    const float* Wfc0 = (const float*)d_in[8];
    const float* bfc0 = (const float*)d_in[9];
    const float* cw1  = (const float*)d_in[10];
    const float* cw2  = (const float*)d_in[11];
    const float* wpt  = (const float*)d_in[12];
    const float* wptb = (const float*)d_in[13];
    const float* nw1  = (const float*)d_in[14];
    const float* nw2  = (const float*)d_in[15];
    const float* nuw  = (const float*)d_in[16];
    const float* nub  = (const float*)d_in[17];
    const float* Wde3 = (const float*)d_in[18];
    const float* bde3 = (const float*)d_in[19];
    const float* Wfc1 = (const float*)d_in[20];
    const float* bfc1 = (const float*)d_in[21];
    const float* Wfc2 = (const float*)d_in[22];
    const float* bfc2 = (const float*)d_in[23];
    float* out = (float*)d_out;

    float* ws     = (float*)d_ws;
    float* hA     = ws;                                   // B*32*G = 524288
    float* hB     = hA + (size_t)BB * WIDTH * GG;         // 524288
    float* xfbuf  = hB + (size_t)BB * WIDTH * GG;         // B*32*128*2 = 65536
    float* Fm     = xfbuf + (size_t)BB * WIDTH * 128 * 2; // B*32*153*2 = 39168
    float* images = Fm + (size_t)BB * WIDTH * 153 * 2;    // B*S*289*2 = 36992
    float* mnmx   = images + (size_t)BB * SS * 289 * 2;   // 256 (unused; kept for layout)
    float* q      = mnmx + 256;                           // B*G = 16384
    float* xnu    = q + (size_t)BB * GG;                  // B*NY = 32768
    float* sttbuf = xnu + (size_t)BB * NYP;               // B*32*64*8*2 = 131072

    k_embed<<<GG / 8, 256, 0, stream>>>(x, loc, We1, be1, We2, be2, Wfc0, bfc0, hA);

    const float* hin = hA;
    float* hout = hB;
    for (int l = 0; l < 4; ++l) {
        k_xf<<<BB * WIDTH, 256, 0, stream>>>(hin, xfbuf);
        k_mix<<<BB * WIDTH, 256, 0, stream>>>(xfbuf,
                                              cw1 + (size_t)l * 16384, cw2 + (size_t)l * 16384,
                                              sttbuf);
        k_pw<<<BB * 64, 256, 0, stream>>>(hin, sttbuf, wpt + l * 1024, wptb + l * 32,
                                          hout, (l < 3) ? 1 : 0);
        float* tmp = (float*)hin; hin = hout; hout = tmp;
    }
    // hin now = hA = final trunk activation
    k_nu_fm<<<BB * WIDTH, 256, 0, stream>>>(hin, Fm);
    k_nu_img<<<BB * SS, 256, 0, stream>>>(Fm, nw1, nw2, images);
    k_nudft<<<BB * SS, 256, 0, stream>>>(ind, sep, loc, images, nuw, nub, xnu);
    k_head<<<(BB * GG) / 256, 256, 0, stream>>>(hin, Wfc1, bfc1, Wfc2, bfc2, q);
    k_de3<<<NYP / 8, 256, 0, stream>>>(Wde3, bde3, q, xnu, out);
}

// Round 6
// 545.140 us; speedup vs baseline: 1.4667x; 1.0485x over previous
//
#include <hip/hip_runtime.h>
#include <math.h>

#define BB 4
#define NX 4096
#define NYP 8192
#define GG 4096
#define WIDTH 32
#define SS 16
#define PI_F 3.14159265358979323846f

__device__ __forceinline__ float gelu_exact(float v) {
    return 0.5f * v * (1.0f + erff(v * 0.70710678118654752f));
}

// ---------------- embed part 1: loc matvec -> raw partials embl[g*8 + ch*4 + b] ----------------
// Split from k_embed so the two weight streams (We2 128MB here, We1 64MB in k_embed_x)
// appear as separate dispatches in the profile. Perf expected ~neutral vs fused (parked regime).
__global__ __launch_bounds__(256, 2) void k_embed_loc(
    const float* __restrict__ loc,
    const float* __restrict__ We2,
    float* __restrict__ embl)
{
    int gbase = blockIdx.x * 8;
    int t = threadIdx.x;

    float accl[64];
    #pragma unroll
    for (int k = 0; k < 64; ++k) accl[k] = 0.f;
    for (int n4 = t; n4 < NYP / 4; n4 += 256) {
        float4 p0[4], p1[4];
        #pragma unroll
        for (int b = 0; b < 4; ++b) {
            const float4* lb = (const float4*)(loc + (size_t)b * NYP * 2);
            p0[b] = lb[n4 * 2];
            p1[b] = lb[n4 * 2 + 1];
        }
        float4 w[8];
        #pragma unroll
        for (int r = 0; r < 8; ++r)
            w[r] = ((const float4*)(We2 + (size_t)(gbase + r) * NYP))[n4];
        #pragma unroll
        for (int r = 0; r < 8; ++r)
            #pragma unroll
            for (int b = 0; b < 4; ++b) {
                accl[r * 4 + b]      += w[r].x * p0[b].x + w[r].y * p0[b].z
                                      + w[r].z * p1[b].x + w[r].w * p1[b].z;
                accl[32 + r * 4 + b] += w[r].x * p0[b].y + w[r].y * p0[b].w
                                      + w[r].z * p1[b].y + w[r].w * p1[b].w;
            }
    }

    #pragma unroll
    for (int k = 0; k < 64; ++k)
        for (int off = 32; off > 0; off >>= 1) accl[k] += __shfl_down(accl[k], off);
    __shared__ float red[4][64];
    __shared__ float tot[64];
    int wave = t >> 6, lane = t & 63;
    if (lane == 0)
        for (int k = 0; k < 64; ++k) red[wave][k] = accl[k];
    __syncthreads();
    if (t < 64) tot[t] = red[0][t] + red[1][t] + red[2][t] + red[3][t];
    __syncthreads();
    if (t < 64) {
        int ch = t >> 5, rb = t & 31, r = rb >> 2, b = rb & 3;
        embl[(size_t)(gbase + r) * 8 + ch * 4 + b] = tot[t];
    }
}

// ---------------- embed part 2: x matvec + fc0 epilogue -> h0 (B,32,64,64) ----------------
__global__ __launch_bounds__(256) void k_embed_x(
    const float* __restrict__ x,
    const float* __restrict__ We1, const float* __restrict__ be1,
    const float* __restrict__ be2,
    const float* __restrict__ Wfc0, const float* __restrict__ bfc0,
    const float* __restrict__ embl,
    float* __restrict__ h0)
{
    int gbase = blockIdx.x * 8;
    int t = threadIdx.x;

    float accx[32];
    #pragma unroll
    for (int k = 0; k < 32; ++k) accx[k] = 0.f;
    for (int n4 = t; n4 < NX / 4; n4 += 256) {
        float4 xb[4];
        #pragma unroll
        for (int b = 0; b < 4; ++b)
            xb[b] = ((const float4*)(x + (size_t)b * NX))[n4];
        float4 w[8];
        #pragma unroll
        for (int r = 0; r < 8; ++r)
            w[r] = ((const float4*)(We1 + (size_t)(gbase + r) * NX))[n4];
        #pragma unroll
        for (int r = 0; r < 8; ++r)
            #pragma unroll
            for (int b = 0; b < 4; ++b)
                accx[r * 4 + b] += w[r].x * xb[b].x + w[r].y * xb[b].y
                                 + w[r].z * xb[b].z + w[r].w * xb[b].w;
    }

    #pragma unroll
    for (int k = 0; k < 32; ++k)
        for (int off = 32; off > 0; off >>= 1) accx[k] += __shfl_down(accx[k], off);
    __shared__ float red[4][32];
    __shared__ float tot[32];
    int wave = t >> 6, lane = t & 63;
    if (lane == 0)
        for (int k = 0; k < 32; ++k) red[wave][k] = accx[k];
    __syncthreads();
    if (t < 32) tot[t] = red[0][t] + red[1][t] + red[2][t] + red[3][t];
    __syncthreads();
    if (t < 128) {
        int b = t >> 5, w = t & 31;
        float w0 = Wfc0[w * 3 + 0], w1c = Wfc0[w * 3 + 1], w2c = Wfc0[w * 3 + 2], bb0 = bfc0[w];
        #pragma unroll
        for (int r = 0; r < 8; ++r) {
            int g = gbase + r;
            float xe = tot[r * 4 + b] + be1[g];
            float l0 = embl[(size_t)g * 8 + b]     + be2[g];
            float l1 = embl[(size_t)g * 8 + 4 + b] + be2[g];
            h0[((size_t)(b * WIDTH + w)) * GG + g] = xe * w0 + l0 * w1c + l1 * w2c + bb0;
        }
    }
}

// ---------------- truncated forward DFT: h(b,c,64,64) -> xf(b,c,16,8) complex ----------------
__global__ __launch_bounds__(256) void k_xf(const float* __restrict__ h, float* __restrict__ xf)
{
    int bc = blockIdx.x;
    int t = threadIdx.x;
    __shared__ float sh[64 * 66];          // padded rows: bank-conflict-free stage-1
    __shared__ float twc[8 * 64], tws[8 * 64];
    __shared__ float tb64c[64], tb64s[64]; // e^{-2*pi*i*m/64}
    __shared__ float s1[64 * 8 * 2];
    const float* hp = h + (size_t)bc * 4096;
    for (int i = t; i < 4096; i += 256) sh[(i >> 6) * 66 + (i & 63)] = hp[i];
    for (int i = t; i < 512; i += 256) {
        int ky = i >> 6, y = i & 63;
        float s, c;
        sincosf(-2.f * PI_F * (float)(ky * y) / 64.f, &s, &c);
        twc[i] = c; tws[i] = s;
    }
    if (t < 64) {
        float s, c;
        sincosf(-2.f * PI_F * (float)t / 64.f, &s, &c);
        tb64c[t] = c; tb64s[t] = s;
    }
    __syncthreads();
    for (int task = t; task < 512; task += 256) {
        int xx = task >> 3, ky = task & 7;
        float sr = 0.f, si = 0.f;
        const float* row = sh + xx * 66;
        const float* tc = twc + ky * 64;
        const float* ts = tws + ky * 64;
        for (int y = 0; y < 64; ++y) { sr += row[y] * tc[y]; si += row[y] * ts[y]; }
        s1[(xx * 8 + ky) * 2 + 0] = sr;
        s1[(xx * 8 + ky) * 2 + 1] = si;
    }
    __syncthreads();
    if (t < 128) {
        int kxi = t >> 3, ky = t & 7;
        int kx = (kxi < 8) ? kxi : (kxi - 16);   // negative freq alias of rows 56..63
        float ar = 0.f, ai = 0.f;
        int m = 0;                               // (kx*xx) mod 64, incremental
        for (int xx = 0; xx < 64; ++xx) {
            float c = tb64c[m], s = tb64s[m];
            float vr = s1[(xx * 8 + ky) * 2], vi = s1[(xx * 8 + ky) * 2 + 1];
            ar += vr * c - vi * s;
            ai += vr * s + vi * c;
            m = (m + kx) & 63;
        }
        xf[((size_t)bc * 128 + t) * 2 + 0] = ar;
        xf[((size_t)bc * 128 + t) * 2 + 1] = ai;
    }
}

// ---------------- mode mix + truncated inverse x-DFT -> stt(b,o,64,8) complex ----------------
__global__ __launch_bounds__(256) void k_mix(
    const float* __restrict__ xf,
    const float* __restrict__ w1, const float* __restrict__ w2,
    float* __restrict__ stt)
{
    int blk = blockIdx.x;
    int b = blk >> 5, o = blk & 31;
    int t = threadIdx.x;
    __shared__ float sxf[32 * 128 * 2];   // 32 KB
    __shared__ float sof2[2][128 * 2];    // split-K partials
    __shared__ float cxc[16 * 64], cxs[16 * 64];   // x-ifft twiddle table, 8 KB
    __shared__ float sw1[32 * 128], sw2[32 * 128]; // per-o weight slices, 32 KB
    const float* xfb = xf + (size_t)b * 32 * 128 * 2;
    for (int i = t; i < 32 * 128 * 2; i += 256) sxf[i] = xfb[i];
    for (int i = t; i < 32 * 128; i += 256) {      // coalesced 128-float rows
        int ii = i >> 7, e = i & 127;
        sw1[i] = w1[((size_t)(ii * 32 + o)) * 128 + e];
        sw2[i] = w2[((size_t)(ii * 32 + o)) * 128 + e];
    }
    for (int i = t; i < 1024; i += 256) {
        int kxi = i >> 6, xx = i & 63;
        int kx = (kxi < 8) ? kxi : (kxi - 16);
        float s, c;
        sincosf(2.f * PI_F * (float)(kx * xx) / 64.f, &s, &c);
        cxc[i] = c; cxs[i] = s;
    }
    __syncthreads();
    {   // of[o] = sum_i xf[i] * w[i,o], i split across two half-blocks
        int half = t >> 7, tt = t & 127;
        int kxi = tt >> 3, ky = tt & 7;
        const float* w = (kxi < 8) ? sw1 : sw2;
        int kxw = kxi & 7;
        int e = (kxw * 8 + ky) * 2;
        float ar = 0.f, ai = 0.f;
        int i0 = half * 16;
        #pragma unroll
        for (int i = 0; i < 16; ++i) {
            int ii = i0 + i;
            float wr = w[ii * 128 + e], wimag = w[ii * 128 + e + 1];
            float xr = sxf[(ii * 128 + tt) * 2], xi = sxf[(ii * 128 + tt) * 2 + 1];
            ar += xr * wr - xi * wimag;
            ai += xr * wimag + xi * wr;
        }
        sof2[half][tt * 2 + 0] = ar; sof2[half][tt * 2 + 1] = ai;
    }
    __syncthreads();
    for (int task = t; task < 512; task += 256) {   // ifft along x (1/64)
        int xx = task >> 3, ky = task & 7;
        float ar = 0.f, ai = 0.f;
        #pragma unroll
        for (int kxi = 0; kxi < 16; ++kxi) {
            float c = cxc[kxi * 64 + xx], s = cxs[kxi * 64 + xx];
            int e = (kxi * 8 + ky) * 2;
            float vr = sof2[0][e]     + sof2[1][e];
            float vi = sof2[0][e + 1] + sof2[1][e + 1];
            ar += vr * c - vi * s;
            ai += vr * s + vi * c;
        }
        stt[(size_t)blk * 1024 + (xx * 8 + ky) * 2 + 0] = ar * (1.f / 64.f);
        stt[(size_t)blk * 1024 + (xx * 8 + ky) * 2 + 1] = ai * (1.f / 64.f);
    }
}

// ---------------- irfft-y + pointwise + gelu: block = (b, xx-row), all 32 out-channels ----------------
__global__ __launch_bounds__(256) void k_pw(
    const float* __restrict__ h, const float* __restrict__ stt,
    const float* __restrict__ wpt, const float* __restrict__ wptb,
    float* __restrict__ hout, int do_gelu)
{
    int blk = blockIdx.x;
    int b = blk >> 6, xx = blk & 63;
    int t = threadIdx.x;
    __shared__ float sh[32 * 64];       // h[c][y] tile, 8 KB
    __shared__ float sst[32 * 16];      // stt[o][ky]{r,i}, 2 KB
    __shared__ float swp[32 * 32];      // wpt[o][c], 4 KB
    __shared__ float swb[32];
    __shared__ float cy[8 * 64], sy[8 * 64];
    for (int i = t; i < 2048; i += 256) {
        int c = i >> 6, y = i & 63;
        sh[i] = h[((size_t)(b * 32 + c)) * 4096 + xx * 64 + y];
    }
    for (int i = t; i < 512; i += 256) {
        int o = i >> 4, r = i & 15;
        sst[i] = stt[((size_t)(b * 32 + o)) * 1024 + xx * 16 + r];
    }
    for (int i = t; i < 1024; i += 256) swp[i] = wpt[i];
    if (t < 32) swb[t] = wptb[t];
    for (int i = t; i < 512; i += 256) {
        int ky = i >> 6, y = i & 63;
        float s, c;
        sincosf(2.f * PI_F * (float)(ky * y) / 64.f, &s, &c);
        cy[i] = c; sy[i] = s;
    }
    __syncthreads();
    int o = t >> 3, y0 = t & 7;
    float wb = swb[o];
    #pragma unroll
    for (int k = 0; k < 8; ++k) {
        int y = y0 + 8 * k;
        // irfft along y, n=64: DC imag dropped (C2R semantics), Nyquist zero
        float sp = sst[o * 16 + 0];
        #pragma unroll
        for (int ky = 1; ky < 8; ++ky)
            sp += 2.f * (sst[o * 16 + ky * 2]     * cy[ky * 64 + y]
                       - sst[o * 16 + ky * 2 + 1] * sy[ky * 64 + y]);
        sp *= (1.f / 64.f);
        float pw = wb;
        #pragma unroll
        for (int c = 0; c < 32; ++c)
            pw += swp[o * 32 + c] * sh[c * 64 + y];
        float v = sp + pw;
        if (do_gelu) v = gelu_exact(v);
        hout[((size_t)(b * 32 + o)) * 4096 + xx * 64 + y] = v;
    }
}

// ---------------- centered 65x65 ortho-FFT modes: Fm(b,c,17,9) a=-8..8, b=-8..0 ----------------
__global__ __launch_bounds__(256) void k_nu_fm(const float* __restrict__ h, float* __restrict__ Fm)
{
    int bc = blockIdx.x;
    int t = threadIdx.x;
    __shared__ float sh[64 * 66];
    __shared__ float twc[9 * 64], tws[9 * 64];
    __shared__ float t65c[65], t65s[65];   // e^{-2*pi*i*m/65}
    __shared__ float s1[64 * 9 * 2];
    const float* hp = h + (size_t)bc * 4096;
    for (int i = t; i < 4096; i += 256) sh[(i >> 6) * 66 + (i & 63)] = hp[i];
    for (int i = t; i < 9 * 64; i += 256) {
        int bbi = i >> 6, y = i & 63;
        float s, c;
        sincosf(-2.f * PI_F * (float)((bbi - 8) * y) / 65.f, &s, &c);
        twc[i] = c; tws[i] = s;
    }
    if (t < 65) {
        float s, c;
        sincosf(-2.f * PI_F * (float)t / 65.f, &s, &c);
        t65c[t] = c; t65s[t] = s;
    }
    __syncthreads();
    for (int task = t; task < 64 * 9; task += 256) {
        int xx = task / 9, bbi = task % 9;
        float sr = 0.f, si = 0.f;
        const float* row = sh + xx * 66;
        const float* tc = twc + bbi * 64;
        const float* ts = tws + bbi * 64;
        for (int y = 0; y < 64; ++y) { sr += row[y] * tc[y]; si += row[y] * ts[y]; }
        s1[(xx * 9 + bbi) * 2 + 0] = sr;
        s1[(xx * 9 + bbi) * 2 + 1] = si;
    }
    __syncthreads();
    for (int task = t; task < 17 * 9; task += 256) {
        int ai2 = task / 9, bbi = task % 9;
        int afreq = ai2 - 8;
        float ar = 0.f, aim = 0.f;
        int m = 0;                             // (afreq*xx) mod 65, incremental
        for (int xx = 0; xx < 64; ++xx) {
            float c = t65c[m], s = t65s[m];
            float vr = s1[(xx * 9 + bbi) * 2], vi = s1[(xx * 9 + bbi) * 2 + 1];
            ar += vr * c - vi * s;
            aim += vr * s + vi * c;
            m += afreq;
            if (m < 0) m += 65;
            else if (m >= 65) m -= 65;
        }
        Fm[((size_t)bc * 153 + task) * 2 + 0] = ar * (1.f / 65.f);
        Fm[((size_t)bc * 153 + task) * 2 + 1] = aim * (1.f / 65.f);
    }
}

// ---------------- mode mix + hermitian image assembly + subdomain bbox ----------------
__global__ __launch_bounds__(256) void k_nu_img(
    const float* __restrict__ Fm, const float* __restrict__ nw1, const float* __restrict__ nw2,
    const int* __restrict__ ind, const int* __restrict__ sep, const float* __restrict__ loc,
    float* __restrict__ images, float* __restrict__ mnmx)
{
    int blk = blockIdx.x;
    int b = blk >> 4, s = blk & 15;
    int t = threadIdx.x;
    __shared__ float im1[17 * 8 * 2];
    __shared__ float im2[9 * 2];
    __shared__ float r[4][256];
    // bbox over this subdomain's points (all 256 threads)
    int j0 = sep[b * 17 + s], j1 = sep[b * 17 + s + 1];
    float mn0 = 1e30f, mn1 = 1e30f, mx0 = -1e30f, mx1 = -1e30f;
    for (int j = j0 + t; j < j1; j += 256) {
        int p = ind[b * NYP + j];
        float l0 = loc[((size_t)b * NYP + p) * 2];
        float l1 = loc[((size_t)b * NYP + p) * 2 + 1];
        mn0 = fminf(mn0, l0); mx0 = fmaxf(mx0, l0);
        mn1 = fminf(mn1, l1); mx1 = fmaxf(mx1, l1);
    }
    r[0][t] = mn0; r[1][t] = mn1; r[2][t] = mx0; r[3][t] = mx1;
    // image mode-mix on threads <145 (independent of bbox shared writes above)
    if (t < 136) {
        int xx = t >> 3, y = t & 7;
        float ar = 0.f, ai = 0.f;
        for (int i = 0; i < 32; ++i) {
            size_t f0 = (((size_t)(b * 32 + i)) * 153 + xx * 9 + y) * 2;
            size_t w0 = (((size_t)(i * 16 + s) * 17 + xx) * 8 + y) * 2;
            float fr = Fm[f0], fi = Fm[f0 + 1];
            float wr = nw1[w0], wi = nw1[w0 + 1];
            ar += fr * wr - fi * wi;
            ai += fr * wi + fi * wr;
        }
        im1[t * 2] = ar; im1[t * 2 + 1] = ai;
    } else if (t < 145) {
        int k = t - 136;   // a = k-8, col b=0 (bbi=8)
        float ar = 0.f, ai = 0.f;
        for (int i = 0; i < 32; ++i) {
            size_t f0 = (((size_t)(b * 32 + i)) * 153 + k * 9 + 8) * 2;
            size_t w0 = ((size_t)(i * 16 + s) * 9 + k) * 2;
            float fr = Fm[f0], fi = Fm[f0 + 1];
            float wr = nw2[w0], wi = nw2[w0 + 1];
            ar += fr * wr - fi * wi;
            ai += fr * wi + fi * wr;
        }
        im2[k * 2] = ar; im2[k * 2 + 1] = ai;
    }
    __syncthreads();
    for (int st = 128; st > 0; st >>= 1) {
        if (t < st) {
            r[0][t] = fminf(r[0][t], r[0][t + st]);
            r[1][t] = fminf(r[1][t], r[1][t + st]);
            r[2][t] = fmaxf(r[2][t], r[2][t + st]);
            r[3][t] = fmaxf(r[3][t], r[3][t + st]);
        }
        __syncthreads();
    }
    if (t == 0) {
        mnmx[blk * 4 + 0] = r[0][0]; mnmx[blk * 4 + 1] = r[1][0];
        mnmx[blk * 4 + 2] = r[2][0]; mnmx[blk * 4 + 3] = r[3][0];
    }
    for (int task = t; task < 289; task += 256) {
        int xx = task / 17, y = task % 17;
        float vr, vi;
        if (y < 8)      { vr = im1[(xx * 8 + y) * 2];            vi = im1[(xx * 8 + y) * 2 + 1]; }
        else if (y > 8) { int sx = 16 - xx, sy2 = 16 - y;
                          vr = im1[(sx * 8 + sy2) * 2];          vi = -im1[(sx * 8 + sy2) * 2 + 1]; }
        else {
            if (xx < 8)       { vr = im2[xx * 2];        vi = im2[xx * 2 + 1]; }
            else if (xx == 8) { vr = im2[16];            vi = 0.f; }
            else              { vr = im2[(16 - xx) * 2]; vi = -im2[(16 - xx) * 2 + 1]; }
        }
        images[((size_t)blk * 289 + task) * 2 + 0] = vr;
        images[((size_t)blk * 289 + task) * 2 + 1] = vi;
    }
}

// ---------------- exact type-2 NUDFT per point: 128 blocks, half-subdomain each ----------------
__global__ __launch_bounds__(256) void k_nudft(
    const int* __restrict__ ind, const int* __restrict__ sep, const float* __restrict__ loc,
    const float* __restrict__ images, const float* __restrict__ mnmx,
    const float* __restrict__ nu_w, const float* __restrict__ nu_b,
    float* __restrict__ xnu)
{
    int blk = blockIdx.x;
    int bs = blk >> 1, half = blk & 1;
    int b = bs >> 4, s = bs & 15;
    int t = threadIdx.x;
    __shared__ float img[289 * 2];
    for (int i = t; i < 578; i += 256) img[i] = images[(size_t)bs * 578 + i];
    __syncthreads();
    int j0 = sep[b * 17 + s], j1 = sep[b * 17 + s + 1];
    int cnt = j1 - j0, per = (cnt + 1) >> 1;
    int st = j0 + half * per;
    int en = min(j1, st + per);
    float mn0 = mnmx[bs * 4], mn1 = mnmx[bs * 4 + 1];
    float mx0 = mnmx[bs * 4 + 2], mx1 = mnmx[bs * 4 + 3];
    float nuw = nu_w[s], nub = nu_b[s];
    const float TWO_PI = 6.28318530717958647692f;
    for (int j = st + t; j < en; j += 256) {
        int p = ind[b * NYP + j];
        float l0 = loc[((size_t)b * NYP + p) * 2];
        float l1 = loc[((size_t)b * NYP + p) * 2 + 1];
        float om0 = (l0 - mn0) / (mx0 - mn0 + 1e-6f) * TWO_PI - PI_F;
        float om1 = (l1 - mn1) / (mx1 - mn1 + 1e-6f) * TWO_PI - PI_F;
        float stepxs, stepxc, stepys, stepyc;
        sincosf(om0, &stepxs, &stepxc);
        sincosf(om1, &stepys, &stepyc);
        float ex_i, ex_r, ey0_i, ey0_r;
        sincosf(-8.f * om0, &ex_i, &ex_r);
        sincosf(-8.f * om1, &ey0_i, &ey0_r);
        float tot = 0.f;
        for (int xx = 0; xx < 17; ++xx) {
            float inr = 0.f, ini = 0.f;
            float eyr = ey0_r, eyi = ey0_i;
            const float* row = img + xx * 34;
            #pragma unroll
            for (int y = 0; y < 17; ++y) {
                float ir = row[y * 2], ii = row[y * 2 + 1];
                inr += ir * eyr - ii * eyi;
                ini += ir * eyi + ii * eyr;
                float nr = eyr * stepyc - eyi * stepys;
                eyi = eyr * stepys + eyi * stepyc;
                eyr = nr;
            }
            tot += ex_r * inr - ex_i * ini;
            float nr = ex_r * stepxc - ex_i * stepxs;
            ex_i = ex_r * stepxs + ex_i * stepxc;
            ex_r = nr;
        }
        xnu[(size_t)b * NYP + p] = (tot * (1.f / 17.f)) * nuw + nub;
    }
}

// ---------------- head MLP: 256 blocks, 64 points each, 4 threads per point ----------------
__global__ __launch_bounds__(256) void k_head(
    const float* __restrict__ h, const float* __restrict__ Wfc1, const float* __restrict__ bfc1,
    const float* __restrict__ Wfc2, const float* __restrict__ bfc2, float* __restrict__ q)
{
    __shared__ float w1s[128 * 32];
    __shared__ float b1s[128];
    __shared__ float w2s[128];
    __shared__ float sacc[4][64];
    int t = threadIdx.x;
    for (int i = t; i < 4096; i += 256) w1s[i] = Wfc1[i];
    if (t < 128) { b1s[t] = bfc1[t]; w2s[t] = Wfc2[t]; }
    __syncthreads();
    int pt = t & 63, jq = t >> 6;
    int id = blockIdx.x * 64 + pt;
    int b = id >> 12, g = id & 4095;
    float hv[32];
    #pragma unroll
    for (int c = 0; c < 32; ++c) hv[c] = h[((size_t)(b * 32 + c)) * GG + g];
    float acc = 0.f;
    int jbase = jq * 32;
    for (int jj = 0; jj < 32; ++jj) {
        int j = jbase + jj;
        float z = b1s[j];
        #pragma unroll
        for (int c = 0; c < 32; ++c) z += w1s[j * 32 + c] * hv[c];
        acc += w2s[j] * gelu_exact(z);
    }
    sacc[jq][pt] = acc;
    __syncthreads();
    if (t < 64) {
        int id2 = blockIdx.x * 64 + t;
        q[id2] = sacc[0][t] + sacc[1][t] + sacc[2][t] + sacc[3][t] + bfc2[0];
    }
}

// ---------------- de3 decoder + final combine with x_nu ----------------
__global__ __launch_bounds__(256) void k_de3(
    const float* __restrict__ Wde3, const float* __restrict__ bde3,
    const float* __restrict__ q, const float* __restrict__ xnu, float* __restrict__ out)
{
    int nbase = blockIdx.x * 8;
    int t = threadIdx.x;
    float acc[32];
    #pragma unroll
    for (int k = 0; k < 32; ++k) acc[k] = 0.f;
    for (int g4 = t; g4 < GG / 4; g4 += 256) {
        float4 qb[4];
        #pragma unroll
        for (int b = 0; b < 4; ++b)
            qb[b] = ((const float4*)(q + (size_t)b * GG))[g4];
        float4 w[8];
        #pragma unroll
        for (int r = 0; r < 8; ++r)
            w[r] = ((const float4*)(Wde3 + (size_t)(nbase + r) * GG))[g4];
        #pragma unroll
        for (int r = 0; r < 8; ++r)
            #pragma unroll
            for (int b = 0; b < 4; ++b)
                acc[r * 4 + b] += w[r].x * qb[b].x + w[r].y * qb[b].y
                                + w[r].z * qb[b].z + w[r].w * qb[b].w;
    }
    #pragma unroll
    for (int k = 0; k < 32; ++k)
        for (int off = 32; off > 0; off >>= 1) acc[k] += __shfl_down(acc[k], off);
    __shared__ float red[4][32];
    int wave = t >> 6, lane = t & 63;
    if (lane == 0)
        for (int k = 0; k < 32; ++k) red[wave][k] = acc[k];
    __syncthreads();
    if (t < 32) {
        float v = red[0][t] + red[1][t] + red[2][t] + red[3][t];
        int r = t >> 2, b = t & 3;
        int n = nbase + r;
        out[(size_t)b * NYP + n] = v + bde3[n] + xnu[(size_t)b * NYP + n];
    }
}

extern "C" void kernel_launch(void* const* d_in, const int* in_sizes, int n_in,
                              void* d_out, int out_size, void* d_ws, size_t ws_size,
                              hipStream_t stream) {
    const float* x    = (const float*)d_in[0];
    const float* loc  = (const float*)d_in[1];
    const int*   ind  = (const int*)d_in[2];
    const int*   sep  = (const int*)d_in[3];
    const float* We1  = (const float*)d_in[4];
    const float* be1  = (const float*)d_in[5];
    const float* We2  = (const float*)d_in[6];
    const float* be2  = (const float*)d_in[7];
    const float* Wfc0 = (const float*)d_in[8];
    const float* bfc0 = (const float*)d_in[9];
    const float* cw1  = (const float*)d_in[10];
    const float* cw2  = (const float*)d_in[11];
    const float* wpt  = (const float*)d_in[12];
    const float* wptb = (const float*)d_in[13];
    const float* nw1  = (const float*)d_in[14];
    const float* nw2  = (const float*)d_in[15];
    const float* nuw  = (const float*)d_in[16];
    const float* nub  = (const float*)d_in[17];
    const float* Wde3 = (const float*)d_in[18];
    const float* bde3 = (const float*)d_in[19];
    const float* Wfc1 = (const float*)d_in[20];
    const float* bfc1 = (const float*)d_in[21];
    const float* Wfc2 = (const float*)d_in[22];
    const float* bfc2 = (const float*)d_in[23];
    float* out = (float*)d_out;

    float* ws     = (float*)d_ws;
    float* hA     = ws;                                   // B*32*G = 524288
    float* hB     = hA + (size_t)BB * WIDTH * GG;         // 524288
    float* xfbuf  = hB + (size_t)BB * WIDTH * GG;         // B*32*128*2 = 65536
    float* Fm     = xfbuf + (size_t)BB * WIDTH * 128 * 2; // B*32*153*2 = 39168
    float* images = Fm + (size_t)BB * WIDTH * 153 * 2;    // B*S*289*2 = 36992
    float* mnmx   = images + (size_t)BB * SS * 289 * 2;   // 256
    float* q      = mnmx + 256;                           // B*G = 16384
    float* xnu    = q + (size_t)BB * GG;                  // B*NY = 32768
    float* sttbuf = xnu + (size_t)BB * NYP;               // B*32*64*8*2 = 131072
    float* embl   = sttbuf + (size_t)BB * WIDTH * 1024;   // G*8 = 32768

    k_embed_loc<<<GG / 8, 256, 0, stream>>>(loc, We2, embl);
    k_embed_x<<<GG / 8, 256, 0, stream>>>(x, We1, be1, be2, Wfc0, bfc0, embl, hA);

    const float* hin = hA;
    float* hout = hB;
    for (int l = 0; l < 4; ++l) {
        k_xf<<<BB * WIDTH, 256, 0, stream>>>(hin, xfbuf);
        k_mix<<<BB * WIDTH, 256, 0, stream>>>(xfbuf,
                                              cw1 + (size_t)l * 16384, cw2 + (size_t)l * 16384,
                                              sttbuf);
        k_pw<<<BB * 64, 256, 0, stream>>>(hin, sttbuf, wpt + l * 1024, wptb + l * 32,
                                          hout, (l < 3) ? 1 : 0);
        float* tmp = (float*)hin; hin = hout; hout = tmp;
    }
    // hin now = hA = final trunk activation
    k_nu_fm<<<BB * WIDTH, 256, 0, stream>>>(hin, Fm);
    k_nu_img<<<BB * SS, 256, 0, stream>>>(Fm, nw1, nw2, ind, sep, loc, images, mnmx);
    k_nudft<<<BB * SS * 2, 256, 0, stream>>>(ind, sep, loc, images, mnmx, nuw, nub, xnu);
    k_head<<<(BB * GG) / 64, 256, 0, stream>>>(hin, Wfc1, bfc1, Wfc2, bfc2, q);
    k_de3<<<NYP / 8, 256, 0, stream>>>(Wde3, bde3, q, xnu, out);
}